// Round 1
// baseline (326.216 us; speedup 1.0000x reference)
//
#include <hip/hip_runtime.h>

#define BTOT 16384
#define NH   64   // humans per batch row
// state row: 64 * 13 floats

// ---------------------------------------------------------------------------
// Pack kernel: lay out streaming weights for the fused kernel.
//  pk[0 .. 2559]   : for k in 0..63: [wh_w1[0..6][k], wh_b1[k], wh_w2[k][0..31]]  (40 floats/k)
//  pk[2560 .. 3583]: W1 column-major: pk[2560 + i*32 + k] = (root_rh1+root_hh1-rel_hh1)[k][i]
// ---------------------------------------------------------------------------
__global__ void pack_weights_kernel(const float* __restrict__ wh_w1,
                                    const float* __restrict__ wh_b1,
                                    const float* __restrict__ wh_w2,
                                    const float* __restrict__ root_rh1,
                                    const float* __restrict__ root_hh1,
                                    const float* __restrict__ rel_hh1,
                                    float* __restrict__ pk) {
    int t = blockIdx.x * blockDim.x + threadIdx.x;
    if (t < 2560) {
        int k = t / 40, m = t % 40;
        float v;
        if (m < 7)       v = wh_w1[m * 64 + k];
        else if (m == 7) v = wh_b1[k];
        else             v = wh_w2[k * 32 + (m - 8)];
        pk[t] = v;
    } else if (t < 3584) {
        int t2 = t - 2560;
        int i = t2 >> 5, k = t2 & 31;
        pk[t] = root_rh1[k * 32 + i] + root_hh1[k * 32 + i] - rel_hh1[k * 32 + i];
    }
}

// ---------------------------------------------------------------------------
// Fused forward: one wave = one batch row (lane = human), block = 4 waves.
// ---------------------------------------------------------------------------
__global__ __launch_bounds__(256) void fused_kernel(
    const float* __restrict__ state,
    const float* __restrict__ pk,
    const float* __restrict__ wr_w1, const float* __restrict__ wr_b1,
    const float* __restrict__ wr_w2, const float* __restrict__ wr_b2,
    const float* __restrict__ wh_b2,
    const float* __restrict__ rel_rh1, const float* __restrict__ brel_rh1,
    const float* __restrict__ rel_hr1, const float* __restrict__ brel_hr1,
    const float* __restrict__ root_hr1,
    const float* __restrict__ rel_hh1, const float* __restrict__ brel_hh1,
    const float* __restrict__ rel_hr2, const float* __restrict__ brel_hr2,
    const float* __restrict__ root_hr2,
    const float* __restrict__ vn_w1, const float* __restrict__ vn_b1,
    const float* __restrict__ vn_w2, const float* __restrict__ vn_b2,
    const float* __restrict__ vn_w3, const float* __restrict__ vn_b3,
    float* __restrict__ out)
{
    __shared__ float lds_t [4][64];
    __shared__ float lds_r [4][32];
    __shared__ float lds_r1[4][32];
    __shared__ float lds_c1[4][32];
    __shared__ float lds_r2[4][32];
    __shared__ float lds_v1[4][152];
    __shared__ float lds_acc[4];

    const int tid  = threadIdx.x;
    const int wave = tid >> 6;
    const int lane = tid & 63;
    const int b    = blockIdx.x * 4 + wave;

    const float* st = state + (size_t)b * (NH * 13);

    // ---------------- r-MLP: hidden (lane k computes t_r[k]) ----------------
    {
        float acc = wr_b1[lane];
        #pragma unroll
        for (int m = 0; m < 6; ++m)
            acc = fmaf(st[m], wr_w1[m * 64 + lane], acc);
        lds_t[wave][lane] = fmaxf(acc, 0.f);
    }
    __syncthreads();
    // r[i], lanes 0..31
    if (lane < 32) {
        float acc = wr_b2[lane];
        #pragma unroll 8
        for (int k = 0; k < 64; ++k)
            acc = fmaf(lds_t[wave][k], wr_w2[k * 32 + lane], acc);
        lds_r[wave][lane] = fmaxf(acc, 0.f);
    }
    __syncthreads();

    // ---------------- h-MLP: 7 -> 64 -> 32, streaming hidden ----------------
    float hs[7];
    {
        const float* hrow = st + lane * 13 + 6;
        #pragma unroll
        for (int m = 0; m < 7; ++m) hs[m] = hrow[m];
    }
    float h[32];
    #pragma unroll
    for (int i = 0; i < 32; ++i) h[i] = wh_b2[i];
    #pragma unroll 2
    for (int k = 0; k < 64; ++k) {
        const float* w = pk + k * 40;          // uniform -> s_load stream
        float tk = w[7];
        #pragma unroll
        for (int m = 0; m < 7; ++m) tk = fmaf(hs[m], w[m], tk);
        tk = fmaxf(tk, 0.f);
        #pragma unroll
        for (int i = 0; i < 32; ++i) h[i] = fmaf(tk, w[8 + i], h[i]);
    }
    #pragma unroll
    for (int i = 0; i < 32; ++i) h[i] = fmaxf(h[i], 0.f);

    // ---------------- sum_h over 64 humans: wave butterfly ----------------
    float s[32];
    #pragma unroll
    for (int i = 0; i < 32; ++i) s[i] = h[i];
    #pragma unroll
    for (int mask = 1; mask < 64; mask <<= 1) {
        #pragma unroll
        for (int i = 0; i < 32; ++i) s[i] += __shfl_xor(s[i], mask, 64);
    }

    // ---------------- layer1 vector ops (lanes 0..31) ----------------
    if (lane < 32) {
        float a1 = 0.f, a2 = 0.f, ca = 0.f, cb = 0.f;
        #pragma unroll
        for (int k = 0; k < 32; ++k) {
            float rk = lds_r[wave][k];
            a1 = fmaf(s[k], rel_hr1 [k * 32 + lane], a1);
            a2 = fmaf(rk,   root_hr1[k * 32 + lane], a2);
            ca = fmaf(rk,   rel_rh1 [k * 32 + lane], ca);
            cb = fmaf(s[k], rel_hh1 [k * 32 + lane], cb);
        }
        lds_r1[wave][lane] = fmaxf(a1 + a2 + brel_hr1[lane], 0.f);
        lds_c1[wave][lane] = ca + cb + brel_rh1[lane] + brel_hh1[lane];
    }
    __syncthreads();

    // ---------------- h2 = relu(c1 + h @ W1), W1 streamed via SGPRs --------
    #pragma unroll
    for (int i = 0; i < 32; ++i) {
        const float* w = pk + 2560 + i * 32;   // column i of W1, uniform
        float acc = lds_c1[wave][i];
        #pragma unroll
        for (int k = 0; k < 32; ++k) acc = fmaf(h[k], w[k], acc);
        s[i] = fmaxf(acc, 0.f);
    }

    // ---------------- sum_h2 butterfly (h2 per-human is dead afterwards) ---
    #pragma unroll
    for (int mask = 1; mask < 64; mask <<= 1) {
        #pragma unroll
        for (int i = 0; i < 32; ++i) s[i] += __shfl_xor(s[i], mask, 64);
    }

    // ---------------- layer2 r2 (lanes 0..31); new_h2 is dead code ---------
    if (lane < 32) {
        float a1 = 0.f, a2 = 0.f;
        #pragma unroll
        for (int k = 0; k < 32; ++k) {
            a1 = fmaf(s[k],             rel_hr2 [k * 32 + lane], a1);
            a2 = fmaf(lds_r1[wave][k],  root_hr2[k * 32 + lane], a2);
        }
        lds_r2[wave][lane] = fmaxf(a1 + a2 + brel_hr2[lane], 0.f);
    }
    __syncthreads();

    // ---------------- value head, block-wide over 4 batch rows -------------
    if (tid < 4) lds_acc[tid] = vn_b3[0];
    // v1 = relu(r2 @ vn_w1 + b1): 150 cols x 4 rows = 600 tasks
    for (int idx = tid; idx < 600; idx += 256) {
        int bi = idx & 3, col = idx >> 2;
        float acc = vn_b1[col];
        #pragma unroll 8
        for (int k = 0; k < 32; ++k)
            acc = fmaf(lds_r2[bi][k], vn_w1[k * 150 + col], acc);
        lds_v1[bi][col] = fmaxf(acc, 0.f);
    }
    __syncthreads();
    // v2 = relu(v1 @ vn_w2 + b2); out = v2 @ vn_w3 + b3 (fused via lds atomics)
    for (int idx = tid; idx < 400; idx += 256) {
        int bi = idx & 3, col = idx >> 2;
        float acc = vn_b2[col];
        #pragma unroll 10
        for (int k = 0; k < 150; ++k)
            acc = fmaf(lds_v1[bi][k], vn_w2[k * 100 + col], acc);
        atomicAdd(&lds_acc[bi], fmaxf(acc, 0.f) * vn_w3[col]);
    }
    __syncthreads();
    if (tid < 4) out[blockIdx.x * 4 + tid] = lds_acc[tid];
}

// ---------------------------------------------------------------------------
extern "C" void kernel_launch(void* const* d_in, const int* in_sizes, int n_in,
                              void* d_out, int out_size, void* d_ws, size_t ws_size,
                              hipStream_t stream) {
    const float* state    = (const float*)d_in[0];
    // d_in[1] = dropout (0, unused)
    const float* wr_w1    = (const float*)d_in[2];
    const float* wr_b1    = (const float*)d_in[3];
    const float* wr_w2    = (const float*)d_in[4];
    const float* wr_b2    = (const float*)d_in[5];
    const float* wh_w1    = (const float*)d_in[6];
    const float* wh_b1    = (const float*)d_in[7];
    const float* wh_w2    = (const float*)d_in[8];
    const float* wh_b2    = (const float*)d_in[9];
    const float* rel_rh1  = (const float*)d_in[10];
    const float* brel_rh1 = (const float*)d_in[11];
    const float* root_rh1 = (const float*)d_in[12];
    const float* rel_hr1  = (const float*)d_in[13];
    const float* brel_hr1 = (const float*)d_in[14];
    const float* root_hr1 = (const float*)d_in[15];
    const float* rel_hh1  = (const float*)d_in[16];
    const float* brel_hh1 = (const float*)d_in[17];
    const float* root_hh1 = (const float*)d_in[18];
    // d_in[19..21] rel_rh2/brel_rh2/root_rh2: dead (layer-2 new_h unused)
    const float* rel_hr2  = (const float*)d_in[22];
    const float* brel_hr2 = (const float*)d_in[23];
    const float* root_hr2 = (const float*)d_in[24];
    // d_in[25..27] rel_hh2/brel_hh2/root_hh2: dead
    const float* vn_w1    = (const float*)d_in[28];
    const float* vn_b1    = (const float*)d_in[29];
    const float* vn_w2    = (const float*)d_in[30];
    const float* vn_b2    = (const float*)d_in[31];
    const float* vn_w3    = (const float*)d_in[32];
    const float* vn_b3    = (const float*)d_in[33];
    float* out = (float*)d_out;
    float* pk  = (float*)d_ws;   // 3584 floats = 14336 B of scratch

    pack_weights_kernel<<<14, 256, 0, stream>>>(wh_w1, wh_b1, wh_w2,
                                                root_rh1, root_hh1, rel_hh1, pk);
    fused_kernel<<<BTOT / 4, 256, 0, stream>>>(state, pk,
        wr_w1, wr_b1, wr_w2, wr_b2, wh_b2,
        rel_rh1, brel_rh1, rel_hr1, brel_hr1, root_hr1,
        rel_hh1, brel_hh1, rel_hr2, brel_hr2, root_hr2,
        vn_w1, vn_b1, vn_w2, vn_b2, vn_w3, vn_b3, out);
}

// Round 2
// 219.270 us; speedup vs baseline: 1.4877x; 1.4877x over previous
//
#include <hip/hip_runtime.h>

#define BTOT 16384

typedef __attribute__((ext_vector_type(8))) short bf16x8;   // 8 bf16 in 4 VGPRs
typedef __attribute__((ext_vector_type(4))) float f32x4;

#define MFMA16(a,b,c) __builtin_amdgcn_mfma_f32_16x16x32_bf16((a),(b),(c),0,0,0)

static __device__ __forceinline__ short f2bf(float x) {
    unsigned u = __float_as_uint(x);
    unsigned r = (u + 0x7FFFu + ((u >> 16) & 1u)) >> 16;   // RNE
    return (short)r;
}
static __device__ __forceinline__ bf16x8 zero8() {
    bf16x8 v;
    #pragma unroll
    for (int i = 0; i < 8; ++i) v[i] = 0;
    return v;
}

// ---------------------------------------------------------------------------
// Workspace layout (bf16 elements in d_ws):
//   [    0, 2048)  Wh1 B-frags   4 ntiles   (k=0..6 weights, k=7 bias, k>7 zero)
//   [ 2048, 4096)  Wh2 B-frags   frag = kt*2+nt  (kt<2, nt<2)
//   [ 4096, 5120)  W1eff B-frags 2 ntiles   (root_rh1+root_hh1-rel_hh1)
//   [ 5120,10240)  vn_w1 B-frags 10 ntiles  (n>=150 zero)
//   [10240,28160)  vn_w2 B-frags frag = kt*7+nt (kt<5, nt<7; k>=150 / n>=100 zero)
//   [28672, +16384*32)  r2 activations, bf16 row-major
// Total ws needed: 57344 + 1048576 bytes ~= 1.06 MB
// ---------------------------------------------------------------------------
__global__ void pack_frags(const float* __restrict__ wh_w1, const float* __restrict__ wh_b1,
                           const float* __restrict__ wh_w2,
                           const float* __restrict__ root_rh1, const float* __restrict__ root_hh1,
                           const float* __restrict__ rel_hh1,
                           const float* __restrict__ vn_w1, const float* __restrict__ vn_w2,
                           short* __restrict__ pk) {
    int t = blockIdx.x * blockDim.x + threadIdx.x;
    if (t >= 28160) return;
    float val = 0.f;
    if (t < 2048) {                                  // Wh1 (+bias at k=7)
        int nt = t >> 9, r = t & 511, lane = r >> 3, j = r & 7;
        int q = lane >> 4, c = lane & 15;
        int k = q * 8 + j, n = nt * 16 + c;
        if (k < 7)       val = wh_w1[k * 64 + n];
        else if (k == 7) val = wh_b1[n];
    } else if (t < 4096) {                           // Wh2
        int u = t - 2048;
        int kt = u >> 10; u &= 1023;
        int nt = u >> 9, r = u & 511, lane = r >> 3, j = r & 7;
        int q = lane >> 4, c = lane & 15;
        int k = kt * 32 + q * 8 + j, n = nt * 16 + c;
        val = wh_w2[k * 32 + n];
    } else if (t < 5120) {                           // W1eff
        int u = t - 4096;
        int nt = u >> 9, r = u & 511, lane = r >> 3, j = r & 7;
        int q = lane >> 4, c = lane & 15;
        int k = q * 8 + j, n = nt * 16 + c;
        val = root_rh1[k * 32 + n] + root_hh1[k * 32 + n] - rel_hh1[k * 32 + n];
    } else if (t < 10240) {                          // vn_w1
        int u = t - 5120;
        int nt = u >> 9, r = u & 511, lane = r >> 3, j = r & 7;
        int q = lane >> 4, c = lane & 15;
        int k = q * 8 + j, n = nt * 16 + c;
        if (n < 150) val = vn_w1[k * 150 + n];
    } else {                                         // vn_w2
        int u = t - 10240;
        int kt = u / 3584; u -= kt * 3584;
        int nt = u >> 9, r = u & 511, lane = r >> 3, j = r & 7;
        int q = lane >> 4, c = lane & 15;
        int k = kt * 32 + q * 8 + j, n = nt * 16 + c;
        if (k < 150 && n < 100) val = vn_w2[k * 100 + n];
    }
    pk[t] = f2bf(val);
}

// ---------------------------------------------------------------------------
// Main fused kernel: wave = one batch row (64 humans = 4 MFMA M-tiles).
// Produces r2 (bf16) into workspace; head is a separate MFMA kernel.
// ---------------------------------------------------------------------------
__global__ __launch_bounds__(256) void fused_main(
    const float* __restrict__ state, const short* __restrict__ pk,
    const float* __restrict__ wr_w1, const float* __restrict__ wr_b1,
    const float* __restrict__ wr_w2, const float* __restrict__ wr_b2,
    const float* __restrict__ wh_b2,
    const float* __restrict__ rel_rh1, const float* __restrict__ brel_rh1,
    const float* __restrict__ rel_hr1, const float* __restrict__ brel_hr1,
    const float* __restrict__ root_hr1,
    const float* __restrict__ rel_hh1, const float* __restrict__ brel_hh1,
    const float* __restrict__ rel_hr2, const float* __restrict__ brel_hr2,
    const float* __restrict__ root_hr2,
    short* __restrict__ r2buf)
{
    // wave-private LDS regions (no inter-wave sharing; barriers only order lanes)
    __shared__ __align__(16) short sh_xa[4][64 * 8];        // features+1.0, A-ready
    __shared__ __align__(16) short sh_t [4][2 * 16 * 72];   // t transpose, double buf
    __shared__ __align__(16) short sh_h [4][64 * 40];       // h (bf16) [human][32]
    __shared__ float sh_trh [4][64];
    __shared__ float sh_rr  [4][32];
    __shared__ float sh_sumh[4][32];
    __shared__ float sh_c1  [4][32];
    __shared__ float sh_r1  [4][32];
    __shared__ float sh_s2  [4][32];

    const int wv = threadIdx.x >> 6, lane = threadIdx.x & 63;
    const int q = lane >> 4, c = lane & 15;
    const int b = blockIdx.x * 4 + wv;
    const float* st = state + (size_t)b * 832;

    // weight B-fragments (wave-uniform, L2-cached)
    const bf16x8* wf = (const bf16x8*)pk;
    bf16x8 bw1[4], bw2[4], bwe[2];
    #pragma unroll
    for (int nt = 0; nt < 4; ++nt) bw1[nt] = wf[nt * 64 + lane];
    #pragma unroll
    for (int f = 0; f < 4; ++f)    bw2[f]  = wf[256 + f * 64 + lane];
    #pragma unroll
    for (int nt = 0; nt < 2; ++nt) bwe[nt] = wf[512 + nt * 64 + lane];

    // ---- stage human features into A-layout (k=0..6 feats, k=7 -> 1.0) ----
    short* xa = sh_xa[wv];
    #pragma unroll
    for (int i = 0; i < 13; ++i) {
        int idx = lane + 64 * i;            // 832 = 13*64 exact
        float v = st[idx];
        int hu = idx / 13, f = idx - hu * 13;
        if (f >= 6) xa[hu * 8 + (f - 6)] = f2bf(v);
    }
    xa[lane * 8 + 7] = 0x3F80;              // bf16(1.0) for the bias row

    // ---- r-MLP hidden layer (lane k -> t_r[k]) ----
    {
        float acc = wr_b1[lane];
        #pragma unroll
        for (int m = 0; m < 6; ++m) acc = fmaf(st[m], wr_w1[m * 64 + lane], acc);
        sh_trh[wv][lane] = fmaxf(acc, 0.f);
    }
    __syncthreads();                         // B1: xa + trh visible

    if (lane < 32) {
        float acc = wr_b2[lane];
        #pragma unroll
        for (int k = 0; k < 64; ++k) acc = fmaf(sh_trh[wv][k], wr_w2[k * 32 + lane], acc);
        sh_rr[wv][lane] = fmaxf(acc, 0.f);
    }

    const float b2a = wh_b2[c], b2b = wh_b2[16 + c];
    short* hb = sh_h[wv];
    const f32x4 z4 = {0.f, 0.f, 0.f, 0.f};
    float shp0 = 0.f, shp1 = 0.f;

    #pragma unroll
    for (int mt = 0; mt < 4; ++mt) {
        short* tb = sh_t[wv] + (mt & 1) * (16 * 72);
        // S1: x[16,32(K, 8 used)] @ Wh1 -> t[16,64]
        bf16x8 a1 = zero8();
        if (q == 0) a1 = *(const bf16x8*)&xa[(mt * 16 + c) * 8];
        f32x4 d0 = MFMA16(a1, bw1[0], z4);
        f32x4 d1 = MFMA16(a1, bw1[1], z4);
        f32x4 d2 = MFMA16(a1, bw1[2], z4);
        f32x4 d3 = MFMA16(a1, bw1[3], z4);
        #pragma unroll
        for (int r = 0; r < 4; ++r) {
            tb[(q * 4 + r) * 72 +  0 + c] = f2bf(fmaxf(d0[r], 0.f));
            tb[(q * 4 + r) * 72 + 16 + c] = f2bf(fmaxf(d1[r], 0.f));
            tb[(q * 4 + r) * 72 + 32 + c] = f2bf(fmaxf(d2[r], 0.f));
            tb[(q * 4 + r) * 72 + 48 + c] = f2bf(fmaxf(d3[r], 0.f));
        }
        __syncthreads();                     // B2..B5: t transpose visible
        // S2: t[16,64] @ Wh2 -> h[16,32]
        bf16x8 a2k0 = *(const bf16x8*)&tb[c * 72 +  0 + q * 8];
        bf16x8 a2k1 = *(const bf16x8*)&tb[c * 72 + 32 + q * 8];
        f32x4 e0 = MFMA16(a2k0, bw2[0], z4); e0 = MFMA16(a2k1, bw2[2], e0);
        f32x4 e1 = MFMA16(a2k0, bw2[1], z4); e1 = MFMA16(a2k1, bw2[3], e1);
        #pragma unroll
        for (int r = 0; r < 4; ++r) {
            float v0 = fmaxf(e0[r] + b2a, 0.f), v1 = fmaxf(e1[r] + b2b, 0.f);
            hb[(mt * 16 + q * 4 + r) * 40 +  0 + c] = f2bf(v0);
            hb[(mt * 16 + q * 4 + r) * 40 + 16 + c] = f2bf(v1);
            shp0 += v0; shp1 += v1;          // per-lane partial of sum_h
        }
    }
    // sum over humans: only 4 shuffles total
    shp0 += __shfl_xor(shp0, 16); shp0 += __shfl_xor(shp0, 32);
    shp1 += __shfl_xor(shp1, 16); shp1 += __shfl_xor(shp1, 32);
    if (lane < 16) { sh_sumh[wv][lane] = shp0; sh_sumh[wv][16 + lane] = shp1; }
    __syncthreads();                         // B6: sum_h + h visible

    // layer1 glue (lanes 0..31): r1 and c1
    if (lane < 32) {
        float a1 = 0.f, a2 = 0.f, ca = 0.f, cb = 0.f;
        #pragma unroll
        for (int k = 0; k < 32; ++k) {
            float sk = sh_sumh[wv][k], rk = sh_rr[wv][k];
            a1 = fmaf(sk, rel_hr1 [k * 32 + lane], a1);
            a2 = fmaf(rk, root_hr1[k * 32 + lane], a2);
            ca = fmaf(rk, rel_rh1 [k * 32 + lane], ca);
            cb = fmaf(sk, rel_hh1 [k * 32 + lane], cb);
        }
        sh_r1[wv][lane] = fmaxf(a1 + a2 + brel_hr1[lane], 0.f);
        sh_c1[wv][lane] = ca + cb + brel_rh1[lane] + brel_hh1[lane];
    }
    __syncthreads();                         // B7: c1/r1 visible

    // S4: h2 = relu(c1 + h @ W1eff), immediately row-summed (per-human h2 is dead)
    const float c1a = sh_c1[wv][c], c1b = sh_c1[wv][16 + c];
    float s2p0 = 0.f, s2p1 = 0.f;
    #pragma unroll
    for (int mt = 0; mt < 4; ++mt) {
        bf16x8 a4 = *(const bf16x8*)&hb[(mt * 16 + c) * 40 + q * 8];
        f32x4 g0 = MFMA16(a4, bwe[0], z4);
        f32x4 g1 = MFMA16(a4, bwe[1], z4);
        #pragma unroll
        for (int r = 0; r < 4; ++r) {
            s2p0 += fmaxf(g0[r] + c1a, 0.f);
            s2p1 += fmaxf(g1[r] + c1b, 0.f);
        }
    }
    s2p0 += __shfl_xor(s2p0, 16); s2p0 += __shfl_xor(s2p0, 32);
    s2p1 += __shfl_xor(s2p1, 16); s2p1 += __shfl_xor(s2p1, 32);
    if (lane < 16) { sh_s2[wv][lane] = s2p0; sh_s2[wv][16 + lane] = s2p1; }
    __syncthreads();                         // B8: s2 visible

    // layer2 glue (lanes 0..31): r2 -> bf16 -> workspace
    if (lane < 32) {
        float a1 = 0.f, a2 = 0.f;
        #pragma unroll
        for (int k = 0; k < 32; ++k) {
            a1 = fmaf(sh_s2[wv][k], rel_hr2 [k * 32 + lane], a1);
            a2 = fmaf(sh_r1[wv][k], root_hr2[k * 32 + lane], a2);
        }
        float r2 = fmaxf(a1 + a2 + brel_hr2[lane], 0.f);
        r2buf[b * 32 + lane] = f2bf(r2);
    }
}

// ---------------------------------------------------------------------------
// Head: r2[16384,32] -> 150 -> 100 -> 1, MFMA, wave = 16 batch rows.
// ---------------------------------------------------------------------------
__global__ __launch_bounds__(256) void head_kernel(
    const short* __restrict__ pk,
    const float* __restrict__ vn_b1, const float* __restrict__ vn_b2,
    const float* __restrict__ vn_w3, const float* __restrict__ vn_b3,
    float* __restrict__ out)
{
    __shared__ __align__(16) short sh_v1[4][16 * 168];   // v1 transpose, K padded to 160
    const int wv = threadIdx.x >> 6, lane = threadIdx.x & 63;
    const int q = lane >> 4, c = lane & 15;
    const int tile = blockIdx.x * 4 + wv;                // 1024 tiles of 16 rows
    const bf16x8* wf = (const bf16x8*)pk;
    const short* r2b = pk + 28672;
    const f32x4 z4 = {0.f, 0.f, 0.f, 0.f};

    bf16x8 a1 = *(const bf16x8*)&r2b[(tile * 16 + c) * 32 + q * 8];
    short* vb = sh_v1[wv];
    #pragma unroll
    for (int nt = 0; nt < 10; ++nt) {
        f32x4 d = MFMA16(a1, wf[640 + nt * 64 + lane], z4);
        int n = nt * 16 + c;
        float bias = (n < 150) ? vn_b1[n] : 0.f;
        #pragma unroll
        for (int r = 0; r < 4; ++r) {
            float v = (n < 150) ? fmaxf(d[r] + bias, 0.f) : 0.f;
            vb[(q * 4 + r) * 168 + n] = f2bf(v);
        }
    }
    __syncthreads();                         // v1 transpose visible

    bf16x8 a2[5];
    #pragma unroll
    for (int kt = 0; kt < 5; ++kt)
        a2[kt] = *(const bf16x8*)&vb[c * 168 + kt * 32 + q * 8];

    float racc[4] = {0.f, 0.f, 0.f, 0.f};
    #pragma unroll
    for (int nt = 0; nt < 7; ++nt) {
        f32x4 d = z4;
        #pragma unroll
        for (int kt = 0; kt < 5; ++kt)
            d = MFMA16(a2[kt], wf[1280 + (kt * 7 + nt) * 64 + lane], d);
        int n = nt * 16 + c;
        float bias = (n < 100) ? vn_b2[n] : 0.f;
        float w3   = (n < 100) ? vn_w3[n] : 0.f;
        #pragma unroll
        for (int r = 0; r < 4; ++r) racc[r] += fmaxf(d[r] + bias, 0.f) * w3;
    }
    #pragma unroll
    for (int m = 1; m < 16; m <<= 1) {
        #pragma unroll
        for (int r = 0; r < 4; ++r) racc[r] += __shfl_xor(racc[r], m);
    }
    if (c == 0) {
        float b3 = vn_b3[0];
        #pragma unroll
        for (int r = 0; r < 4; ++r) out[tile * 16 + q * 4 + r] = racc[r] + b3;
    }
}

// ---------------------------------------------------------------------------
extern "C" void kernel_launch(void* const* d_in, const int* in_sizes, int n_in,
                              void* d_out, int out_size, void* d_ws, size_t ws_size,
                              hipStream_t stream) {
    const float* state    = (const float*)d_in[0];
    const float* wr_w1    = (const float*)d_in[2];
    const float* wr_b1    = (const float*)d_in[3];
    const float* wr_w2    = (const float*)d_in[4];
    const float* wr_b2    = (const float*)d_in[5];
    const float* wh_w1    = (const float*)d_in[6];
    const float* wh_b1    = (const float*)d_in[7];
    const float* wh_w2    = (const float*)d_in[8];
    const float* wh_b2    = (const float*)d_in[9];
    const float* rel_rh1  = (const float*)d_in[10];
    const float* brel_rh1 = (const float*)d_in[11];
    const float* root_rh1 = (const float*)d_in[12];
    const float* rel_hr1  = (const float*)d_in[13];
    const float* brel_hr1 = (const float*)d_in[14];
    const float* root_hr1 = (const float*)d_in[15];
    const float* rel_hh1  = (const float*)d_in[16];
    const float* brel_hh1 = (const float*)d_in[17];
    const float* root_hh1 = (const float*)d_in[18];
    // 19..21 rel_rh2/brel_rh2/root_rh2 dead; 25..27 rel_hh2/... dead
    const float* rel_hr2  = (const float*)d_in[22];
    const float* brel_hr2 = (const float*)d_in[23];
    const float* root_hr2 = (const float*)d_in[24];
    const float* vn_w1    = (const float*)d_in[28];
    const float* vn_b1    = (const float*)d_in[29];
    const float* vn_w2    = (const float*)d_in[30];
    const float* vn_b2    = (const float*)d_in[31];
    const float* vn_w3    = (const float*)d_in[32];
    const float* vn_b3    = (const float*)d_in[33];
    float* out = (float*)d_out;
    short* pk  = (short*)d_ws;               // needs ~1.06 MB of workspace
    short* r2buf = pk + 28672;

    pack_frags<<<110, 256, 0, stream>>>(wh_w1, wh_b1, wh_w2,
                                        root_rh1, root_hh1, rel_hh1,
                                        vn_w1, vn_w2, pk);
    fused_main<<<BTOT / 4, 256, 0, stream>>>(state, pk,
        wr_w1, wr_b1, wr_w2, wr_b2, wh_b2,
        rel_rh1, brel_rh1, rel_hr1, brel_hr1, root_hr1,
        rel_hh1, brel_hh1, rel_hr2, brel_hr2, root_hr2,
        r2buf);
    head_kernel<<<BTOT / 64, 256, 0, stream>>>(pk, vn_b1, vn_b2, vn_w3, vn_b3, out);
}

// Round 4
// 186.980 us; speedup vs baseline: 1.7447x; 1.1727x over previous
//
#include <hip/hip_runtime.h>

#define BTOT 16384

typedef __attribute__((ext_vector_type(8))) short bf16x8;   // 8 bf16 in 4 VGPRs
typedef __attribute__((ext_vector_type(4))) float f32x4;

#define MFMA16(a,b,c) __builtin_amdgcn_mfma_f32_16x16x32_bf16((a),(b),(c),0,0,0)

static __device__ __forceinline__ unsigned short bfhi(float x) {
    unsigned u = __float_as_uint(x);
    return (unsigned short)((u + 0x7FFFu + ((u >> 16) & 1u)) >> 16);   // RNE
}
static __device__ __forceinline__ float b2f(unsigned short h) {
    return __uint_as_float(((unsigned)h) << 16);
}
static __device__ __forceinline__ unsigned short bflo(float x) {
    unsigned short h = bfhi(x);
    return bfhi(x - b2f(h));
}
static __device__ __forceinline__ unsigned pk2(float a, float b) {
    return (unsigned)bfhi(a) | ((unsigned)bfhi(b) << 16);
}
static __device__ __forceinline__ short f2s(float x) {
    return (short)bfhi(x);
}
static __device__ __forceinline__ bf16x8 zero8() {
    bf16x8 v;
    #pragma unroll
    for (int i = 0; i < 8; ++i) v[i] = 0;
    return v;
}

// ---------------------------------------------------------------------------
// Workspace (shorts). Frags are 512 shorts each, frag f at pk[f*512 + lane*8 + j].
// f 0..3 A1 | 4..7 Bh2 | 8..9 Be | 10..21 BrL2(split K=192) | 22..45 Bg1(split)
// | 46..57 Bg2(split) | 58..67 Bv1 | 68..102 Bv2.
// shorts 52736..52864: bg1 f32[64]; 52864..52928: bg2 f32[32];
// 53248..+524288: r2 bf16. Total ~1.16 MB.
// ---------------------------------------------------------------------------
__global__ void pack_frags(
    const float* __restrict__ wh_w1, const float* __restrict__ wh_b1,
    const float* __restrict__ wh_w2,
    const float* __restrict__ root_rh1, const float* __restrict__ root_hh1,
    const float* __restrict__ rel_hh1,
    const float* __restrict__ wr_w2,
    const float* __restrict__ rel_hr1, const float* __restrict__ root_hr1,
    const float* __restrict__ rel_rh1,
    const float* __restrict__ rel_hr2, const float* __restrict__ root_hr2,
    const float* __restrict__ vn_w1, const float* __restrict__ vn_w2,
    const float* __restrict__ brel_hr1, const float* __restrict__ brel_rh1,
    const float* __restrict__ brel_hh1, const float* __restrict__ brel_hr2,
    short* __restrict__ pk)
{
    int t = blockIdx.x * blockDim.x + threadIdx.x;
    if (t < 52736) {
        int f = t >> 9, r = t & 511;
        int lane = r >> 3, j = r & 7;
        int q = lane >> 4, c = lane & 15;
        int k = q * 8 + j;
        unsigned short outv;
        if (f < 4) {                                   // A1: Wh1^T (+bias row k=7)
            int m = f * 16 + c;
            float v = (k < 7) ? wh_w1[k * 64 + m] : (k == 7 ? wh_b1[m] : 0.f);
            outv = bfhi(v);
        } else if (f < 8) {                            // Bh2
            int u = f - 4, ks = u >> 1, nt = u & 1;
            outv = bfhi(wh_w2[(ks * 32 + k) * 32 + nt * 16 + c]);
        } else if (f < 10) {                           // Be (W1eff)
            int n = (f - 8) * 16 + c;
            outv = bfhi(root_rh1[k * 32 + n] + root_hh1[k * 32 + n] - rel_hh1[k * 32 + n]);
        } else if (f < 22) {                           // BrL2 split
            int u = f - 10, ks = u >> 1, nt = u & 1;
            int kp = ks * 32 + k;                      // 0..191
            float w = wr_w2[(kp & 63) * 32 + nt * 16 + c];
            outv = (kp < 128) ? bfhi(w) : bflo(w);
        } else if (f < 46) {                           // Bg1 split
            int u = f - 22, ks = u >> 2, nt = u & 3;
            int kp = ks * 32 + k, seg = kp >> 5, kk = kp & 31;
            int n2 = (nt & 1) * 16 + c;
            bool sPart = (seg < 2) || (seg == 4);
            const float* W = (nt < 2) ? (sPart ? rel_hr1 : root_hr1)
                                      : (sPart ? rel_hh1 : rel_rh1);
            float w = W[kk * 32 + n2];
            outv = (seg < 4) ? bfhi(w) : bflo(w);
        } else if (f < 58) {                           // Bg2 split
            int u = f - 46, ks = u >> 1, nt = u & 1;
            int kp = ks * 32 + k, seg = kp >> 5, kk = kp & 31;
            int n = nt * 16 + c;
            bool sPart = (seg < 2) || (seg == 4);
            const float* W = sPart ? rel_hr2 : root_hr2;
            float w = W[kk * 32 + n];
            outv = (seg < 4) ? bfhi(w) : bflo(w);
        } else if (f < 68) {                           // Bv1
            int n = (f - 58) * 16 + c;
            outv = (n < 150) ? bfhi(vn_w1[k * 150 + n]) : 0;
        } else {                                       // Bv2
            int u = f - 68, kt = u / 7, nt = u - kt * 7;
            int kk = kt * 32 + k, n = nt * 16 + c;
            outv = (kk < 150 && n < 100) ? bfhi(vn_w2[kk * 100 + n]) : 0;
        }
        pk[t] = (short)outv;
    } else if (t < 52800) {
        int i = t - 52736;
        float* bp = (float*)(pk + 52736);
        bp[i] = (i < 32) ? brel_hr1[i] : brel_rh1[i - 32] + brel_hh1[i - 32];
    } else if (t < 52832) {
        int i = t - 52800;
        float* bp = (float*)(pk + 52864);
        bp[i] = brel_hr2[i];
    }
}

// ---------------------------------------------------------------------------
// Main fused kernel: wave = one batch row; per-wave LDS region wbuf[wv]
// (4608 shorts) with overlays: t(pitch 72)[0..4608) / xa[0..512) /
// h(pitch 40)[0..2560) / c1 f32[2560..2624) / g2in[2624..2816) /
// sbuf[2816..3008) / trh[3008..3200). Main-path LDS handoffs are
// within-wave (in-order LDS pipe, no barrier); 3 block barriers for glue.
// ---------------------------------------------------------------------------
__global__ __launch_bounds__(256) void fused_main(
    const float* __restrict__ state, const short* __restrict__ pk,
    const float* __restrict__ wr_w1, const float* __restrict__ wr_b1,
    const float* __restrict__ wr_b2, const float* __restrict__ wh_b2,
    short* __restrict__ r2buf)
{
    __shared__ short wbuf[4][4608];

    const int tid = threadIdx.x;
    const int wv = tid >> 6, lane = tid & 63;
    const int q = lane >> 4, c = lane & 15;
    const int b = blockIdx.x * 4 + wv;
    const float* st = state + (size_t)b * 832;
    short* T = wbuf[wv];

    const bf16x8* pk16 = (const bf16x8*)pk;
    const float* bg1f = (const float*)(pk + 52736);
    const float* bg2f = (const float*)(pk + 52864);
    const f32x4 z4 = {0.f, 0.f, 0.f, 0.f};

    bf16x8 A1[4], Bh2v[4], Bev[2];
    #pragma unroll
    for (int i = 0; i < 4; ++i) A1[i] = pk16[i * 64 + lane];
    #pragma unroll
    for (int i = 0; i < 4; ++i) Bh2v[i] = pk16[(4 + i) * 64 + lane];
    #pragma unroll
    for (int i = 0; i < 2; ++i) Bev[i] = pk16[(8 + i) * 64 + lane];

    {   // own human's features -> LDS, B-ready (k=0..6 feats, k=7 -> 1.0)
        float hf[7];
        #pragma unroll
        for (int m = 0; m < 7; ++m) hf[m] = st[lane * 13 + 6 + m];
        uint4 v = make_uint4(pk2(hf[0], hf[1]), pk2(hf[2], hf[3]),
                             pk2(hf[4], hf[5]), pk2(hf[6], 1.0f));
        *(uint4*)(T + lane * 8) = v;
    }

    float trh;   // r-MLP hidden (lane = hidden unit)
    {
        float acc = wr_b1[lane];
        #pragma unroll
        for (int m = 0; m < 6; ++m) acc = fmaf(st[m], wr_w1[m * 64 + lane], acc);
        trh = fmaxf(acc, 0.f);
    }

    asm volatile("s_waitcnt lgkmcnt(0)" ::: "memory");

    bf16x8 bx[4];
    #pragma unroll
    for (int ht = 0; ht < 4; ++ht) {
        bf16x8 v = zero8();
        if (q == 0) v = *(const bf16x8*)(T + (ht * 16 + c) * 8);
        bx[ht] = v;
    }

    // S1': t^T = Wh1^T @ x^T  (lane holds 4 consecutive hid per human -> b64 writes)
    #pragma unroll
    for (int mh = 0; mh < 4; ++mh) {
        #pragma unroll
        for (int ht = 0; ht < 4; ++ht) {
            f32x4 d = MFMA16(A1[mh], bx[ht], z4);
            uint2 w = make_uint2(pk2(fmaxf(d[0], 0.f), fmaxf(d[1], 0.f)),
                                 pk2(fmaxf(d[2], 0.f), fmaxf(d[3], 0.f)));
            *(uint2*)(T + (ht * 16 + c) * 72 + mh * 16 + q * 4) = w;
        }
    }

    asm volatile("s_waitcnt lgkmcnt(0)" ::: "memory");

    // S2: h = t @ Wh2 (+b2, relu); h rows (pitch 40) + s partials
    const float b2a = wh_b2[c], b2b = wh_b2[16 + c];
    float ps0 = 0.f, ps1 = 0.f;
    #pragma unroll
    for (int mt = 0; mt < 4; ++mt) {
        bf16x8 a0 = *(const bf16x8*)(T + (mt * 16 + c) * 72 + q * 8);
        bf16x8 a1 = *(const bf16x8*)(T + (mt * 16 + c) * 72 + 32 + q * 8);
        f32x4 e0 = MFMA16(a0, Bh2v[0], z4); e0 = MFMA16(a1, Bh2v[2], e0);
        f32x4 e1 = MFMA16(a0, Bh2v[1], z4); e1 = MFMA16(a1, Bh2v[3], e1);
        #pragma unroll
        for (int r = 0; r < 4; ++r) {
            float v0 = fmaxf(e0[r] + b2a, 0.f), v1 = fmaxf(e1[r] + b2b, 0.f);
            int row = mt * 16 + q * 4 + r;
            T[row * 40 + c]      = f2s(v0);
            T[row * 40 + 16 + c] = f2s(v1);
            ps0 += v0; ps1 += v1;
        }
    }
    ps0 += __shfl_xor(ps0, 16); ps0 += __shfl_xor(ps0, 32);
    ps1 += __shfl_xor(ps1, 16); ps1 += __shfl_xor(ps1, 32);

    {   // s -> sbuf row: [s_hi;s_lo;r_hi;r_lo;s_hi;r_hi], trh -> [hi;lo;hi]
        short* SB = T + 2816;
        if (q == 0) {
            unsigned short h0 = bfhi(ps0), h1 = bfhi(ps1);
            SB[c] = (short)h0;        SB[16 + c] = (short)h1;
            SB[32 + c] = (short)bfhi(ps0 - b2f(h0));
            SB[48 + c] = (short)bfhi(ps1 - b2f(h1));
            SB[128 + c] = (short)h0;  SB[144 + c] = (short)h1;
        }
        short* TR = T + 3008;
        unsigned short th = bfhi(trh);
        TR[lane] = (short)th;
        TR[64 + lane] = (short)bfhi(trh - b2f(th));
        TR[128 + lane] = (short)th;
    }
    __syncthreads();   // B1

    if (wv == 0) {     // rL2 + glue1 for the block's 4 rows (split-bf16 K=192)
        bf16x8 art[6];
        #pragma unroll
        for (int ks = 0; ks < 6; ++ks) {
            bf16x8 v = zero8();
            if (c < 4) v = *(const bf16x8*)(wbuf[c] + 3008 + ks * 32 + q * 8);
            art[ks] = v;
        }
        f32x4 dr0 = z4, dr1 = z4;
        #pragma unroll
        for (int ks = 0; ks < 6; ++ks) {
            dr0 = MFMA16(art[ks], pk16[(10 + ks * 2 + 0) * 64 + lane], dr0);
            dr1 = MFMA16(art[ks], pk16[(10 + ks * 2 + 1) * 64 + lane], dr1);
        }
        const float wb0 = wr_b2[c], wb1 = wr_b2[16 + c];
        if (q == 0) {
            #pragma unroll
            for (int r = 0; r < 4; ++r) {
                float v0 = fmaxf(dr0[r] + wb0, 0.f), v1 = fmaxf(dr1[r] + wb1, 0.f);
                short* SBr = wbuf[r] + 2816;
                unsigned short h0 = bfhi(v0), h1 = bfhi(v1);
                SBr[64 + c] = (short)h0;  SBr[96 + c]  = (short)bfhi(v0 - b2f(h0));  SBr[160 + c] = (short)h0;
                SBr[80 + c] = (short)h1;  SBr[112 + c] = (short)bfhi(v1 - b2f(h1));  SBr[176 + c] = (short)h1;
            }
        }
        asm volatile("s_waitcnt lgkmcnt(0)" ::: "memory");

        bf16x8 ag[6];
        #pragma unroll
        for (int ks = 0; ks < 6; ++ks) {
            bf16x8 v = zero8();
            if (c < 4) v = *(const bf16x8*)(wbuf[c] + 2816 + ks * 32 + q * 8);
            ag[ks] = v;
        }
        f32x4 dg[4] = {z4, z4, z4, z4};
        #pragma unroll
        for (int ks = 0; ks < 6; ++ks) {
            #pragma unroll
            for (int nt = 0; nt < 4; ++nt)
                dg[nt] = MFMA16(ag[ks], pk16[(22 + ks * 4 + nt) * 64 + lane], dg[nt]);
        }
        if (q == 0) {
            #pragma unroll
            for (int nt = 0; nt < 2; ++nt) {
                float bias = bg1f[nt * 16 + c];
                #pragma unroll
                for (int r = 0; r < 4; ++r) {
                    float v = fmaxf(dg[nt][r] + bias, 0.f);
                    short* G2r = wbuf[r] + 2624;
                    unsigned short hh = bfhi(v);
                    G2r[64 + nt * 16 + c]  = (short)hh;
                    G2r[96 + nt * 16 + c]  = (short)bfhi(v - b2f(hh));
                    G2r[160 + nt * 16 + c] = (short)hh;
                }
            }
            #pragma unroll
            for (int nt = 2; nt < 4; ++nt) {
                float bias = bg1f[nt * 16 + c];
                #pragma unroll
                for (int r = 0; r < 4; ++r)
                    ((float*)(wbuf[r] + 2560))[(nt - 2) * 16 + c] = dg[nt][r] + bias;
            }
        }
    }
    __syncthreads();   // B2

    {   // S4: s2 = sum_hu relu(c1 + h @ W1eff)
        const float* C1 = (const float*)(T + 2560);
        const float c10 = C1[c], c11 = C1[16 + c];
        float t0 = 0.f, t1 = 0.f;
        #pragma unroll
        for (int mt = 0; mt < 4; ++mt) {
            bf16x8 ah = *(const bf16x8*)(T + (mt * 16 + c) * 40 + q * 8);
            f32x4 g0 = MFMA16(ah, Bev[0], z4);
            f32x4 g1 = MFMA16(ah, Bev[1], z4);
            #pragma unroll
            for (int r = 0; r < 4; ++r) {
                t0 += fmaxf(g0[r] + c10, 0.f);
                t1 += fmaxf(g1[r] + c11, 0.f);
            }
        }
        t0 += __shfl_xor(t0, 16); t0 += __shfl_xor(t0, 32);
        t1 += __shfl_xor(t1, 16); t1 += __shfl_xor(t1, 32);
        short* G2 = T + 2624;
        if (q == 0) {
            unsigned short h0 = bfhi(t0), h1 = bfhi(t1);
            G2[c] = (short)h0;        G2[16 + c] = (short)h1;
            G2[32 + c] = (short)bfhi(t0 - b2f(h0));
            G2[48 + c] = (short)bfhi(t1 - b2f(h1));
            G2[128 + c] = (short)h0;  G2[144 + c] = (short)h1;
        }
    }
    __syncthreads();   // B3

    if (wv == 0) {     // glue2 -> r2
        bf16x8 a2[6];
        #pragma unroll
        for (int ks = 0; ks < 6; ++ks) {
            bf16x8 v = zero8();
            if (c < 4) v = *(const bf16x8*)(wbuf[c] + 2624 + ks * 32 + q * 8);
            a2[ks] = v;
        }
        f32x4 d0 = z4, d1 = z4;
        #pragma unroll
        for (int ks = 0; ks < 6; ++ks) {
            d0 = MFMA16(a2[ks], pk16[(46 + ks * 2 + 0) * 64 + lane], d0);
            d1 = MFMA16(a2[ks], pk16[(46 + ks * 2 + 1) * 64 + lane], d1);
        }
        if (q == 0) {
            const int b0 = blockIdx.x * 4;
            const float g0 = bg2f[c], g1 = bg2f[16 + c];
            #pragma unroll
            for (int r = 0; r < 4; ++r) {
                r2buf[(b0 + r) * 32 + c]      = f2s(fmaxf(d0[r] + g0, 0.f));
                r2buf[(b0 + r) * 32 + 16 + c] = f2s(fmaxf(d1[r] + g1, 0.f));
            }
        }
    }
}

// ---------------------------------------------------------------------------
__global__ __launch_bounds__(256) void head_kernel(
    const short* __restrict__ pk,
    const float* __restrict__ vn_b1, const float* __restrict__ vn_b2,
    const float* __restrict__ vn_w3, const float* __restrict__ vn_b3,
    float* __restrict__ out)
{
    __shared__ __align__(16) short sh_v1[4][16 * 168];
    const int wv = threadIdx.x >> 6, lane = threadIdx.x & 63;
    const int q = lane >> 4, c = lane & 15;
    const int tile = blockIdx.x * 4 + wv;
    const bf16x8* wf = (const bf16x8*)pk;
    const short* r2b = pk + 53248;
    const f32x4 z4 = {0.f, 0.f, 0.f, 0.f};

    bf16x8 a1 = *(const bf16x8*)&r2b[(tile * 16 + c) * 32 + q * 8];
    short* vb = sh_v1[wv];
    #pragma unroll
    for (int nt = 0; nt < 10; ++nt) {
        f32x4 d = MFMA16(a1, wf[(58 + nt) * 64 + lane], z4);
        int n = nt * 16 + c;
        float bias = (n < 150) ? vn_b1[n] : 0.f;
        #pragma unroll
        for (int r = 0; r < 4; ++r) {
            float v = (n < 150) ? fmaxf(d[r] + bias, 0.f) : 0.f;
            vb[(q * 4 + r) * 168 + n] = f2s(v);
        }
    }
    __syncthreads();

    bf16x8 a2[5];
    #pragma unroll
    for (int kt = 0; kt < 5; ++kt)
        a2[kt] = *(const bf16x8*)&vb[c * 168 + kt * 32 + q * 8];

    float racc[4] = {0.f, 0.f, 0.f, 0.f};
    #pragma unroll
    for (int nt = 0; nt < 7; ++nt) {
        f32x4 d = z4;
        #pragma unroll
        for (int kt = 0; kt < 5; ++kt)
            d = MFMA16(a2[kt], wf[(68 + kt * 7 + nt) * 64 + lane], d);
        int n = nt * 16 + c;
        float bias = (n < 100) ? vn_b2[n] : 0.f;
        float w3   = (n < 100) ? vn_w3[n] : 0.f;
        #pragma unroll
        for (int r = 0; r < 4; ++r) racc[r] += fmaxf(d[r] + bias, 0.f) * w3;
    }
    #pragma unroll
    for (int m = 1; m < 16; m <<= 1) {
        #pragma unroll
        for (int r = 0; r < 4; ++r) racc[r] += __shfl_xor(racc[r], m);
    }
    if (c == 0) {
        float b3 = vn_b3[0];
        #pragma unroll
        for (int r = 0; r < 4; ++r) out[tile * 16 + q * 4 + r] = racc[r] + b3;
    }
}

// ---------------------------------------------------------------------------
extern "C" void kernel_launch(void* const* d_in, const int* in_sizes, int n_in,
                              void* d_out, int out_size, void* d_ws, size_t ws_size,
                              hipStream_t stream) {
    const float* state    = (const float*)d_in[0];
    const float* wr_w1    = (const float*)d_in[2];
    const float* wr_b1    = (const float*)d_in[3];
    const float* wr_w2    = (const float*)d_in[4];
    const float* wr_b2    = (const float*)d_in[5];
    const float* wh_w1    = (const float*)d_in[6];
    const float* wh_b1    = (const float*)d_in[7];
    const float* wh_w2    = (const float*)d_in[8];
    const float* wh_b2    = (const float*)d_in[9];
    const float* rel_rh1  = (const float*)d_in[10];
    const float* brel_rh1 = (const float*)d_in[11];
    const float* root_rh1 = (const float*)d_in[12];
    const float* rel_hr1  = (const float*)d_in[13];
    const float* brel_hr1 = (const float*)d_in[14];
    const float* root_hr1 = (const float*)d_in[15];
    const float* rel_hh1  = (const float*)d_in[16];
    const float* brel_hh1 = (const float*)d_in[17];
    const float* root_hh1 = (const float*)d_in[18];
    // 19..21, 25..27 dead (layer-2 new_h unused)
    const float* rel_hr2  = (const float*)d_in[22];
    const float* brel_hr2 = (const float*)d_in[23];
    const float* root_hr2 = (const float*)d_in[24];
    const float* vn_w1    = (const float*)d_in[28];
    const float* vn_b1    = (const float*)d_in[29];
    const float* vn_w2    = (const float*)d_in[30];
    const float* vn_b2    = (const float*)d_in[31];
    const float* vn_w3    = (const float*)d_in[32];
    const float* vn_b3    = (const float*)d_in[33];
    float* out = (float*)d_out;
    short* pk  = (short*)d_ws;               // needs ~1.16 MB of workspace
    short* r2buf = pk + 53248;

    pack_frags<<<207, 256, 0, stream>>>(wh_w1, wh_b1, wh_w2,
                                        root_rh1, root_hh1, rel_hh1, wr_w2,
                                        rel_hr1, root_hr1, rel_rh1,
                                        rel_hr2, root_hr2, vn_w1, vn_w2,
                                        brel_hr1, brel_rh1, brel_hh1, brel_hr2, pk);
    fused_main<<<BTOT / 4, 256, 0, stream>>>(state, pk, wr_w1, wr_b1, wr_b2, wh_b2, r2buf);
    head_kernel<<<BTOT / 64, 256, 0, stream>>>(pk, vn_b1, vn_b2, vn_w3, vn_b3, out);
}

// Round 5
// 183.702 us; speedup vs baseline: 1.7758x; 1.0178x over previous
//
#include <hip/hip_runtime.h>

#define BTOT 16384

typedef __attribute__((ext_vector_type(8))) short bf16x8;   // 8 bf16 in 4 VGPRs
typedef __attribute__((ext_vector_type(4))) float f32x4;

#define MFMA16(a,b,c) __builtin_amdgcn_mfma_f32_16x16x32_bf16((a),(b),(c),0,0,0)

// ---- bf16 conversion helpers: HW packed cvt if available, manual RNE else ----
#if __has_builtin(__builtin_amdgcn_cvt_pk_bf16_f32)
typedef __attribute__((ext_vector_type(2))) __bf16 hwbf2;
static __device__ __forceinline__ unsigned pk2(float a, float b) {
    hwbf2 v = __builtin_amdgcn_cvt_pk_bf16_f32(a, b);
    return __builtin_bit_cast(unsigned, v);
}
#else
static __device__ __forceinline__ unsigned pk2(float a, float b) {
    unsigned ua = __float_as_uint(a), ub = __float_as_uint(b);
    unsigned ra = (ua + 0x7FFFu + ((ua >> 16) & 1u)) >> 16;
    unsigned rb = (ub + 0x7FFFu + ((ub >> 16) & 1u)) >> 16;
    return (ra & 0xFFFFu) | (rb << 16);
}
#endif
static __device__ __forceinline__ unsigned short bfhi(float x) {
    return (unsigned short)(pk2(x, 0.f) & 0xFFFFu);
}
static __device__ __forceinline__ float b2f(unsigned short h) {
    return __uint_as_float(((unsigned)h) << 16);
}
static __device__ __forceinline__ short f2s(float x) { return (short)bfhi(x); }
// host-side-exact manual RNE for the pack kernel (identical rounding)
static __device__ __forceinline__ unsigned short bfhi_m(float x) {
    unsigned u = __float_as_uint(x);
    return (unsigned short)((u + 0x7FFFu + ((u >> 16) & 1u)) >> 16);
}
static __device__ __forceinline__ unsigned short bflo_m(float x) {
    unsigned short h = bfhi_m(x);
    return bfhi_m(x - b2f(h));
}
static __device__ __forceinline__ bf16x8 zero8() {
    bf16x8 v;
    #pragma unroll
    for (int i = 0; i < 8; ++i) v[i] = 0;
    return v;
}

// ---------------------------------------------------------------------------
// Workspace (shorts). Frags are 512 shorts each, frag f at pk[f*512 + lane*8 + j].
// f 0..3 A1 | 4..7 Bh2 | 8..9 Be (K-permuted: k_old=(k>>1)+((k&1)<<4)) |
// 10..21 BrL2(split K=192) | 22..45 Bg1(split) | 46..57 Bg2(split) |
// 58..67 Bv1 | 68..102 Bv2.
// shorts 52736..52864: bg1 f32[64]; 52864..52928: bg2 f32[32];
// 53248..+524288: r2 bf16. Total ~1.16 MB.
// ---------------------------------------------------------------------------
__global__ void pack_frags(
    const float* __restrict__ wh_w1, const float* __restrict__ wh_b1,
    const float* __restrict__ wh_w2,
    const float* __restrict__ root_rh1, const float* __restrict__ root_hh1,
    const float* __restrict__ rel_hh1,
    const float* __restrict__ wr_w2,
    const float* __restrict__ rel_hr1, const float* __restrict__ root_hr1,
    const float* __restrict__ rel_rh1,
    const float* __restrict__ rel_hr2, const float* __restrict__ root_hr2,
    const float* __restrict__ vn_w1, const float* __restrict__ vn_w2,
    const float* __restrict__ brel_hr1, const float* __restrict__ brel_rh1,
    const float* __restrict__ brel_hh1, const float* __restrict__ brel_hr2,
    short* __restrict__ pk)
{
    int t = blockIdx.x * blockDim.x + threadIdx.x;
    if (t < 52736) {
        int f = t >> 9, r = t & 511;
        int lane = r >> 3, j = r & 7;
        int q = lane >> 4, c = lane & 15;
        int k = q * 8 + j;
        unsigned short outv;
        if (f < 4) {                                   // A1: Wh1^T (+bias row k=7)
            int m = f * 16 + c;
            float v = (k < 7) ? wh_w1[k * 64 + m] : (k == 7 ? wh_b1[m] : 0.f);
            outv = bfhi_m(v);
        } else if (f < 8) {                            // Bh2
            int u = f - 4, ks = u >> 1, nt = u & 1;
            outv = bfhi_m(wh_w2[(ks * 32 + k) * 32 + nt * 16 + c]);
        } else if (f < 10) {                           // Be (W1eff), K-permuted for
            int n = (f - 8) * 16 + c;                  // interleaved h layout
            int ko = (k >> 1) + ((k & 1) << 4);
            outv = bfhi_m(root_rh1[ko * 32 + n] + root_hh1[ko * 32 + n] - rel_hh1[ko * 32 + n]);
        } else if (f < 22) {                           // BrL2 split
            int u = f - 10, ks = u >> 1, nt = u & 1;
            int kp = ks * 32 + k;                      // 0..191
            float w = wr_w2[(kp & 63) * 32 + nt * 16 + c];
            outv = (kp < 128) ? bfhi_m(w) : bflo_m(w);
        } else if (f < 46) {                           // Bg1 split
            int u = f - 22, ks = u >> 2, nt = u & 3;
            int kp = ks * 32 + k, seg = kp >> 5, kk = kp & 31;
            int n2 = (nt & 1) * 16 + c;
            bool sPart = (seg < 2) || (seg == 4);
            const float* W = (nt < 2) ? (sPart ? rel_hr1 : root_hr1)
                                      : (sPart ? rel_hh1 : rel_rh1);
            float w = W[kk * 32 + n2];
            outv = (seg < 4) ? bfhi_m(w) : bflo_m(w);
        } else if (f < 58) {                           // Bg2 split
            int u = f - 46, ks = u >> 1, nt = u & 1;
            int kp = ks * 32 + k, seg = kp >> 5, kk = kp & 31;
            int n = nt * 16 + c;
            bool sPart = (seg < 2) || (seg == 4);
            const float* W = sPart ? rel_hr2 : root_hr2;
            float w = W[kk * 32 + n];
            outv = (seg < 4) ? bfhi_m(w) : bflo_m(w);
        } else if (f < 68) {                           // Bv1
            int n = (f - 58) * 16 + c;
            outv = (n < 150) ? bfhi_m(vn_w1[k * 150 + n]) : 0;
        } else {                                       // Bv2
            int u = f - 68, kt = u / 7, nt = u - kt * 7;
            int kk = kt * 32 + k, n = nt * 16 + c;
            outv = (kk < 150 && n < 100) ? bfhi_m(vn_w2[kk * 100 + n]) : 0;
        }
        pk[t] = (short)outv;
    } else if (t < 52800) {
        int i = t - 52736;
        float* bp = (float*)(pk + 52736);
        bp[i] = (i < 32) ? brel_hr1[i] : brel_rh1[i - 32] + brel_hh1[i - 32];
    } else if (t < 52832) {
        int i = t - 52800;
        float* bp = (float*)(pk + 52864);
        bp[i] = brel_hr2[i];
    }
}

// ---------------------------------------------------------------------------
// Main fused kernel: wave = one batch row; per-wave T[4096 shorts] (8 KB).
// t: rows 0..63 at row*64, XOR-swizzled 16B units (unit ^= row&7).
// h: rows 0..63 at row*32, cols interleaved (2c,2c+1)=(c,16+c), swizzle row&3.
// Overlays (tail): c1 f32 @3456, g2in @3520, sbuf @3712, trh @3904 — all
// written only after the t rows they overlay are consumed (in-order DS pipe).
// ---------------------------------------------------------------------------
__global__ __launch_bounds__(256) void fused_main(
    const float* __restrict__ state, const short* __restrict__ pk,
    const float* __restrict__ wr_w1, const float* __restrict__ wr_b1,
    const float* __restrict__ wr_b2, const float* __restrict__ wh_b2,
    short* __restrict__ r2buf)
{
    __shared__ short wbuf[4][4096];

    const int tid = threadIdx.x;
    const int wv = tid >> 6, lane = tid & 63;
    const int q = lane >> 4, c = lane & 15;
    const int b = blockIdx.x * 4 + wv;
    const float* st = state + (size_t)b * 832;
    short* T = wbuf[wv];

    const bf16x8* pk16 = (const bf16x8*)pk;
    const float* bg1f = (const float*)(pk + 52736);
    const float* bg2f = (const float*)(pk + 52864);
    const f32x4 z4 = {0.f, 0.f, 0.f, 0.f};

    bf16x8 A1[4], Bh2v[4], Bev[2];
    #pragma unroll
    for (int i = 0; i < 4; ++i) A1[i] = pk16[i * 64 + lane];
    #pragma unroll
    for (int i = 0; i < 4; ++i) Bh2v[i] = pk16[(4 + i) * 64 + lane];
    #pragma unroll
    for (int i = 0; i < 2; ++i) Bev[i] = pk16[(8 + i) * 64 + lane];

    {   // own human's features -> LDS, B-ready (k=0..6 feats, k=7 -> 1.0)
        float hf[7];
        #pragma unroll
        for (int m = 0; m < 7; ++m) hf[m] = st[lane * 13 + 6 + m];
        uint4 v = make_uint4(pk2(hf[0], hf[1]), pk2(hf[2], hf[3]),
                             pk2(hf[4], hf[5]), pk2(hf[6], 1.0f));
        *(uint4*)(T + lane * 8) = v;
    }

    float trh;   // r-MLP hidden (lane = hidden unit)
    {
        float acc = wr_b1[lane];
        #pragma unroll
        for (int m = 0; m < 6; ++m) acc = fmaf(st[m], wr_w1[m * 64 + lane], acc);
        trh = fmaxf(acc, 0.f);
    }

    asm volatile("s_waitcnt lgkmcnt(0)" ::: "memory");

    bf16x8 bx[4];
    #pragma unroll
    for (int ht = 0; ht < 4; ++ht) {
        bf16x8 v = zero8();
        if (q == 0) v = *(const bf16x8*)(T + (ht * 16 + c) * 8);
        bx[ht] = v;
    }

    // S1': t^T = Wh1^T @ x^T; swizzled b64 writes (unit 2mh+(q>>1), key c&7)
    #pragma unroll
    for (int mh = 0; mh < 4; ++mh) {
        #pragma unroll
        for (int ht = 0; ht < 4; ++ht) {
            f32x4 d = MFMA16(A1[mh], bx[ht], z4);
            uint2 w = make_uint2(pk2(fmaxf(d[0], 0.f), fmaxf(d[1], 0.f)),
                                 pk2(fmaxf(d[2], 0.f), fmaxf(d[3], 0.f)));
            int row = ht * 16 + c;
            int u = (2 * mh + (q >> 1)) ^ (c & 7);
            *(uint2*)(T + row * 64 + u * 8 + (q & 1) * 4) = w;
        }
    }

    asm volatile("s_waitcnt lgkmcnt(0)" ::: "memory");

    // S2: h = t @ Wh2 (+b2, relu); packed-pair h rows (pitch 32) + s partials
    const float b2a = wh_b2[c], b2b = wh_b2[16 + c];
    float ps0 = 0.f, ps1 = 0.f;
    #pragma unroll
    for (int mt = 0; mt < 4; ++mt) {
        int row = mt * 16 + c;
        bf16x8 a0 = *(const bf16x8*)(T + row * 64 + ((q ^ (c & 7))) * 8);
        bf16x8 a1 = *(const bf16x8*)(T + row * 64 + (((q + 4) ^ (c & 7))) * 8);
        f32x4 e0 = MFMA16(a0, Bh2v[0], z4); e0 = MFMA16(a1, Bh2v[2], e0);
        f32x4 e1 = MFMA16(a0, Bh2v[1], z4); e1 = MFMA16(a1, Bh2v[3], e1);
        #pragma unroll
        for (int r = 0; r < 4; ++r) {
            float v0 = fmaxf(e0[r] + b2a, 0.f), v1 = fmaxf(e1[r] + b2b, 0.f);
            int hrow = mt * 16 + q * 4 + r;
            *(unsigned*)(T + hrow * 32 + (((c >> 2) ^ r)) * 8 + (c & 3) * 2) = pk2(v0, v1);
            ps0 += v0; ps1 += v1;
        }
    }
    ps0 += __shfl_xor(ps0, 16); ps0 += __shfl_xor(ps0, 32);
    ps1 += __shfl_xor(ps1, 16); ps1 += __shfl_xor(ps1, 32);

    {   // s -> sbuf: [s_hi;s_lo;r_hi;r_lo;s_hi;r_hi], trh -> [hi;lo;hi]
        short* SB = T + 3712;
        if (q == 0) {
            unsigned short h0 = bfhi(ps0), h1 = bfhi(ps1);
            SB[c] = (short)h0;        SB[16 + c] = (short)h1;
            SB[32 + c] = (short)bfhi(ps0 - b2f(h0));
            SB[48 + c] = (short)bfhi(ps1 - b2f(h1));
            SB[128 + c] = (short)h0;  SB[144 + c] = (short)h1;
        }
        short* TR = T + 3904;
        unsigned short th = bfhi(trh);
        TR[lane] = (short)th;
        TR[64 + lane] = (short)bfhi(trh - b2f(th));
        TR[128 + lane] = (short)th;
    }
    __syncthreads();   // B1

    if (wv == 0) {     // rL2 + glue1 for the block's 4 rows (split-bf16 K=192)
        bf16x8 art[6];
        #pragma unroll
        for (int ks = 0; ks < 6; ++ks) {
            bf16x8 v = zero8();
            if (c < 4) v = *(const bf16x8*)(wbuf[c] + 3904 + ks * 32 + q * 8);
            art[ks] = v;
        }
        f32x4 dr0 = z4, dr1 = z4;
        #pragma unroll
        for (int ks = 0; ks < 6; ++ks) {
            dr0 = MFMA16(art[ks], pk16[(10 + ks * 2 + 0) * 64 + lane], dr0);
            dr1 = MFMA16(art[ks], pk16[(10 + ks * 2 + 1) * 64 + lane], dr1);
        }
        const float wb0 = wr_b2[c], wb1 = wr_b2[16 + c];
        if (q == 0) {
            #pragma unroll
            for (int r = 0; r < 4; ++r) {
                float v0 = fmaxf(dr0[r] + wb0, 0.f), v1 = fmaxf(dr1[r] + wb1, 0.f);
                short* SBr = wbuf[r] + 3712;
                unsigned short h0 = bfhi(v0), h1 = bfhi(v1);
                SBr[64 + c] = (short)h0;  SBr[96 + c]  = (short)bfhi(v0 - b2f(h0));  SBr[160 + c] = (short)h0;
                SBr[80 + c] = (short)h1;  SBr[112 + c] = (short)bfhi(v1 - b2f(h1));  SBr[176 + c] = (short)h1;
            }
        }
        asm volatile("s_waitcnt lgkmcnt(0)" ::: "memory");

        bf16x8 ag[6];
        #pragma unroll
        for (int ks = 0; ks < 6; ++ks) {
            bf16x8 v = zero8();
            if (c < 4) v = *(const bf16x8*)(wbuf[c] + 3712 + ks * 32 + q * 8);
            ag[ks] = v;
        }
        f32x4 dg[4] = {z4, z4, z4, z4};
        #pragma unroll
        for (int ks = 0; ks < 6; ++ks) {
            #pragma unroll
            for (int nt = 0; nt < 4; ++nt)
                dg[nt] = MFMA16(ag[ks], pk16[(22 + ks * 4 + nt) * 64 + lane], dg[nt]);
        }
        if (q == 0) {
            #pragma unroll
            for (int nt = 0; nt < 2; ++nt) {
                float bias = bg1f[nt * 16 + c];
                #pragma unroll
                for (int r = 0; r < 4; ++r) {       // r1 -> g2in
                    float v = fmaxf(dg[nt][r] + bias, 0.f);
                    short* G2r = wbuf[r] + 3520;
                    unsigned short hh = bfhi(v);
                    G2r[64 + nt * 16 + c]  = (short)hh;
                    G2r[96 + nt * 16 + c]  = (short)bfhi(v - b2f(hh));
                    G2r[160 + nt * 16 + c] = (short)hh;
                }
            }
            #pragma unroll
            for (int nt = 2; nt < 4; ++nt) {
                float bias = bg1f[nt * 16 + c];
                #pragma unroll
                for (int r = 0; r < 4; ++r)         // c1 (f32, no relu)
                    ((float*)(wbuf[r] + 3456))[(nt - 2) * 16 + c] = dg[nt][r] + bias;
            }
        }
    }
    __syncthreads();   // B2

    {   // S4: s2 = sum_hu relu(c1 + h @ W1eff)   (h interleaved, Be K-permuted)
        const float* C1 = (const float*)(T + 3456);
        const float c10 = C1[c], c11 = C1[16 + c];
        float t0 = 0.f, t1 = 0.f;
        #pragma unroll
        for (int mt = 0; mt < 4; ++mt) {
            int row = mt * 16 + c;
            bf16x8 ah = *(const bf16x8*)(T + row * 32 + ((q ^ (c & 3))) * 8);
            f32x4 g0 = MFMA16(ah, Bev[0], z4);
            f32x4 g1 = MFMA16(ah, Bev[1], z4);
            #pragma unroll
            for (int r = 0; r < 4; ++r) {
                t0 += fmaxf(g0[r] + c10, 0.f);
                t1 += fmaxf(g1[r] + c11, 0.f);
            }
        }
        t0 += __shfl_xor(t0, 16); t0 += __shfl_xor(t0, 32);
        t1 += __shfl_xor(t1, 16); t1 += __shfl_xor(t1, 32);
        short* G2 = T + 3520;   // [s2_hi(32); s2_lo(32); r1...; s2_hi(32); r1...]
        if (q == 0) {
            unsigned short h0 = bfhi(t0), h1 = bfhi(t1);
            G2[c] = (short)h0;        G2[16 + c] = (short)h1;
            G2[32 + c] = (short)bfhi(t0 - b2f(h0));
            G2[48 + c] = (short)bfhi(t1 - b2f(h1));
            G2[128 + c] = (short)h0;  G2[144 + c] = (short)h1;
        }
    }
    __syncthreads();   // B3

    if (wv == 0) {     // glue2 -> r2
        bf16x8 a2[6];
        #pragma unroll
        for (int ks = 0; ks < 6; ++ks) {
            bf16x8 v = zero8();
            if (c < 4) v = *(const bf16x8*)(wbuf[c] + 3520 + ks * 32 + q * 8);
            a2[ks] = v;
        }
        f32x4 d0 = z4, d1 = z4;
        #pragma unroll
        for (int ks = 0; ks < 6; ++ks) {
            d0 = MFMA16(a2[ks], pk16[(46 + ks * 2 + 0) * 64 + lane], d0);
            d1 = MFMA16(a2[ks], pk16[(46 + ks * 2 + 1) * 64 + lane], d1);
        }
        if (q == 0) {
            const int b0 = blockIdx.x * 4;
            const float g0 = bg2f[c], g1 = bg2f[16 + c];
            #pragma unroll
            for (int r = 0; r < 4; ++r) {
                r2buf[(b0 + r) * 32 + c]      = f2s(fmaxf(d0[r] + g0, 0.f));
                r2buf[(b0 + r) * 32 + 16 + c] = f2s(fmaxf(d1[r] + g1, 0.f));
            }
        }
    }
}

// ---------------------------------------------------------------------------
__global__ __launch_bounds__(256) void head_kernel(
    const short* __restrict__ pk,
    const float* __restrict__ vn_b1, const float* __restrict__ vn_b2,
    const float* __restrict__ vn_w3, const float* __restrict__ vn_b3,
    float* __restrict__ out)
{
    __shared__ __align__(16) short sh_v1[4][16 * 168];
    const int wv = threadIdx.x >> 6, lane = threadIdx.x & 63;
    const int q = lane >> 4, c = lane & 15;
    const int tile = blockIdx.x * 4 + wv;
    const bf16x8* wf = (const bf16x8*)pk;
    const short* r2b = pk + 53248;
    const f32x4 z4 = {0.f, 0.f, 0.f, 0.f};

    bf16x8 a1 = *(const bf16x8*)&r2b[(tile * 16 + c) * 32 + q * 8];
    short* vb = sh_v1[wv];
    #pragma unroll
    for (int nt = 0; nt < 10; ++nt) {
        f32x4 d = MFMA16(a1, wf[(58 + nt) * 64 + lane], z4);
        int n = nt * 16 + c;
        float bias = (n < 150) ? vn_b1[n] : 0.f;
        #pragma unroll
        for (int r = 0; r < 4; ++r) {
            float v = (n < 150) ? fmaxf(d[r] + bias, 0.f) : 0.f;
            vb[(q * 4 + r) * 168 + n] = f2s(v);
        }
    }
    __syncthreads();

    bf16x8 a2[5];
    #pragma unroll
    for (int kt = 0; kt < 5; ++kt)
        a2[kt] = *(const bf16x8*)&vb[c * 168 + kt * 32 + q * 8];

    float racc[4] = {0.f, 0.f, 0.f, 0.f};
    #pragma unroll
    for (int nt = 0; nt < 7; ++nt) {
        f32x4 d = z4;
        #pragma unroll
        for (int kt = 0; kt < 5; ++kt)
            d = MFMA16(a2[kt], wf[(68 + kt * 7 + nt) * 64 + lane], d);
        int n = nt * 16 + c;
        float bias = (n < 100) ? vn_b2[n] : 0.f;
        float w3   = (n < 100) ? vn_w3[n] : 0.f;
        #pragma unroll
        for (int r = 0; r < 4; ++r) racc[r] += fmaxf(d[r] + bias, 0.f) * w3;
    }
    #pragma unroll
    for (int m = 1; m < 16; m <<= 1) {
        #pragma unroll
        for (int r = 0; r < 4; ++r) racc[r] += __shfl_xor(racc[r], m);
    }
    if (c == 0) {
        float b3 = vn_b3[0];
        #pragma unroll
        for (int r = 0; r < 4; ++r) out[tile * 16 + q * 4 + r] = racc[r] + b3;
    }
}

// ---------------------------------------------------------------------------
extern "C" void kernel_launch(void* const* d_in, const int* in_sizes, int n_in,
                              void* d_out, int out_size, void* d_ws, size_t ws_size,
                              hipStream_t stream) {
    const float* state    = (const float*)d_in[0];
    const float* wr_w1    = (const float*)d_in[2];
    const float* wr_b1    = (const float*)d_in[3];
    const float* wr_w2    = (const float*)d_in[4];
    const float* wr_b2    = (const float*)d_in[5];
    const float* wh_w1    = (const float*)d_in[6];
    const float* wh_b1    = (const float*)d_in[7];
    const float* wh_w2    = (const float*)d_in[8];
    const float* wh_b2    = (const float*)d_in[9];
    const float* rel_rh1  = (const float*)d_in[10];
    const float* brel_rh1 = (const float*)d_in[11];
    const float* root_rh1 = (const float*)d_in[12];
    const float* rel_hr1  = (const float*)d_in[13];
    const float* brel_hr1 = (const float*)d_in[14];
    const float* root_hr1 = (const float*)d_in[15];
    const float* rel_hh1  = (const float*)d_in[16];
    const float* brel_hh1 = (const float*)d_in[17];
    const float* root_hh1 = (const float*)d_in[18];
    // 19..21, 25..27 dead (layer-2 new_h unused)
    const float* rel_hr2  = (const float*)d_in[22];
    const float* brel_hr2 = (const float*)d_in[23];
    const float* root_hr2 = (const float*)d_in[24];
    const float* vn_w1    = (const float*)d_in[28];
    const float* vn_b1    = (const float*)d_in[29];
    const float* vn_w2    = (const float*)d_in[30];
    const float* vn_b2    = (const float*)d_in[31];
    const float* vn_w3    = (const float*)d_in[32];
    const float* vn_b3    = (const float*)d_in[33];
    float* out = (float*)d_out;
    short* pk  = (short*)d_ws;               // needs ~1.16 MB of workspace
    short* r2buf = pk + 53248;

    pack_frags<<<207, 256, 0, stream>>>(wh_w1, wh_b1, wh_w2,
                                        root_rh1, root_hh1, rel_hh1, wr_w2,
                                        rel_hr1, root_hr1, rel_rh1,
                                        rel_hr2, root_hr2, vn_w1, vn_w2,
                                        brel_hr1, brel_rh1, brel_hh1, brel_hr2, pk);
    fused_main<<<BTOT / 4, 256, 0, stream>>>(state, pk, wr_w1, wr_b1, wr_b2, wh_b2, r2buf);
    head_kernel<<<BTOT / 64, 256, 0, stream>>>(pk, vn_b1, vn_b2, vn_w3, vn_b3, out);
}

// Round 6
// 183.571 us; speedup vs baseline: 1.7771x; 1.0007x over previous
//
#include <hip/hip_runtime.h>

#define BTOT 16384

typedef __attribute__((ext_vector_type(8))) short bf16x8;   // 8 bf16 in 4 VGPRs
typedef __attribute__((ext_vector_type(4))) float f32x4;

#define MFMA16(a,b,c) __builtin_amdgcn_mfma_f32_16x16x32_bf16((a),(b),(c),0,0,0)

// ---- bf16 conversion helpers: HW packed cvt if available, manual RNE else ----
#if __has_builtin(__builtin_amdgcn_cvt_pk_bf16_f32)
typedef __attribute__((ext_vector_type(2))) __bf16 hwbf2;
static __device__ __forceinline__ unsigned pk2(float a, float b) {
    hwbf2 v = __builtin_amdgcn_cvt_pk_bf16_f32(a, b);
    return __builtin_bit_cast(unsigned, v);
}
#else
static __device__ __forceinline__ unsigned pk2(float a, float b) {
    unsigned ua = __float_as_uint(a), ub = __float_as_uint(b);
    unsigned ra = (ua + 0x7FFFu + ((ua >> 16) & 1u)) >> 16;
    unsigned rb = (ub + 0x7FFFu + ((ub >> 16) & 1u)) >> 16;
    return (ra & 0xFFFFu) | (rb << 16);
}
#endif
static __device__ __forceinline__ unsigned short bfhi(float x) {
    return (unsigned short)(pk2(x, 0.f) & 0xFFFFu);
}
static __device__ __forceinline__ float b2f(unsigned short h) {
    return __uint_as_float(((unsigned)h) << 16);
}
static __device__ __forceinline__ short f2s(float x) { return (short)bfhi(x); }
// manual RNE for the pack kernel (identical rounding either path)
static __device__ __forceinline__ unsigned short bfhi_m(float x) {
    unsigned u = __float_as_uint(x);
    return (unsigned short)((u + 0x7FFFu + ((u >> 16) & 1u)) >> 16);
}
static __device__ __forceinline__ unsigned short bflo_m(float x) {
    unsigned short h = bfhi_m(x);
    return bfhi_m(x - b2f(h));
}
static __device__ __forceinline__ bf16x8 zero8() {
    bf16x8 v;
    #pragma unroll
    for (int i = 0; i < 8; ++i) v[i] = 0;
    return v;
}

// ---------------------------------------------------------------------------
// Workspace (shorts). Frags are 512 shorts each, frag f at pk[f*512 + lane*8 + j].
// f 0..3 A1 | 4..7 Bh2 (K-order matched to paired-b128 t storage) |
// 8..9 Be (K-permuted: k_old=(k>>1)+((k&1)<<4)) | 10..21 BrL2(split K=192) |
// 22..45 Bg1(split) | 46..57 Bg2(split) | 58..67 Bv1 | 68..102 Bv2.
// shorts 52736..52864: bg1 f32[64]; 52864..52928: bg2 f32[32];
// 53248..+524288: r2 bf16. Total ~1.16 MB.
// ---------------------------------------------------------------------------
__global__ void pack_frags(
    const float* __restrict__ wh_w1, const float* __restrict__ wh_b1,
    const float* __restrict__ wh_w2,
    const float* __restrict__ root_rh1, const float* __restrict__ root_hh1,
    const float* __restrict__ rel_hh1,
    const float* __restrict__ wr_w2,
    const float* __restrict__ rel_hr1, const float* __restrict__ root_hr1,
    const float* __restrict__ rel_rh1,
    const float* __restrict__ rel_hr2, const float* __restrict__ root_hr2,
    const float* __restrict__ vn_w1, const float* __restrict__ vn_w2,
    const float* __restrict__ brel_hr1, const float* __restrict__ brel_rh1,
    const float* __restrict__ brel_hh1, const float* __restrict__ brel_hr2,
    short* __restrict__ pk)
{
    int t = blockIdx.x * blockDim.x + threadIdx.x;
    if (t < 52736) {
        int f = t >> 9, r = t & 511;
        int lane = r >> 3, j = r & 7;
        int q = lane >> 4, c = lane & 15;
        int k = q * 8 + j;
        unsigned short outv;
        if (f < 4) {                                   // A1: Wh1^T (+bias row k=7)
            int m = f * 16 + c;
            float v = (k < 7) ? wh_w1[k * 64 + m] : (k == 7 ? wh_b1[m] : 0.f);
            outv = bfhi_m(v);
        } else if (f < 8) {                            // Bh2; K-order for paired t
            int u = f - 4, ks = u >> 1, nt = u & 1;
            int kr = ks * 32 + (j >> 2) * 16 + q * 4 + (j & 3);
            outv = bfhi_m(wh_w2[kr * 32 + nt * 16 + c]);
        } else if (f < 10) {                           // Be (W1eff), K-permuted for
            int n = (f - 8) * 16 + c;                  // interleaved h layout
            int ko = (k >> 1) + ((k & 1) << 4);
            outv = bfhi_m(root_rh1[ko * 32 + n] + root_hh1[ko * 32 + n] - rel_hh1[ko * 32 + n]);
        } else if (f < 22) {                           // BrL2 split
            int u = f - 10, ks = u >> 1, nt = u & 1;
            int kp = ks * 32 + k;                      // 0..191
            float w = wr_w2[(kp & 63) * 32 + nt * 16 + c];
            outv = (kp < 128) ? bfhi_m(w) : bflo_m(w);
        } else if (f < 46) {                           // Bg1 split
            int u = f - 22, ks = u >> 2, nt = u & 3;
            int kp = ks * 32 + k, seg = kp >> 5, kk = kp & 31;
            int n2 = (nt & 1) * 16 + c;
            bool sPart = (seg < 2) || (seg == 4);
            const float* W = (nt < 2) ? (sPart ? rel_hr1 : root_hr1)
                                      : (sPart ? rel_hh1 : rel_rh1);
            float w = W[kk * 32 + n2];
            outv = (seg < 4) ? bfhi_m(w) : bflo_m(w);
        } else if (f < 58) {                           // Bg2 split
            int u = f - 46, ks = u >> 1, nt = u & 1;
            int kp = ks * 32 + k, seg = kp >> 5, kk = kp & 31;
            int n = nt * 16 + c;
            bool sPart = (seg < 2) || (seg == 4);
            const float* W = sPart ? rel_hr2 : root_hr2;
            float w = W[kk * 32 + n];
            outv = (seg < 4) ? bfhi_m(w) : bflo_m(w);
        } else if (f < 68) {                           // Bv1
            int n = (f - 58) * 16 + c;
            outv = (n < 150) ? bfhi_m(vn_w1[k * 150 + n]) : 0;
        } else {                                       // Bv2
            int u = f - 68, kt = u / 7, nt = u - kt * 7;
            int kk = kt * 32 + k, n = nt * 16 + c;
            outv = (kk < 150 && n < 100) ? bfhi_m(vn_w2[kk * 100 + n]) : 0;
        }
        pk[t] = (short)outv;
    } else if (t < 52800) {
        int i = t - 52736;
        float* bp = (float*)(pk + 52736);
        bp[i] = (i < 32) ? brel_hr1[i] : brel_rh1[i - 32] + brel_hh1[i - 32];
    } else if (t < 52832) {
        int i = t - 52800;
        float* bp = (float*)(pk + 52864);
        bp[i] = brel_hr2[i];
    }
}

// ---------------------------------------------------------------------------
// Main fused kernel: wave = one batch row; per-wave T[4096 shorts] (8 KB).
// t: rows 0..63 at row*64 shorts, 8 b128 units/row, unit p = (mhp*4+q)^(c&7).
// h: rows 0..63 at row*32, cols interleaved, unit swizzle ^(row&3).
// Tail overlays (written only after the t rows they alias are consumed):
// c1 f32 @3456, g2in @3520, sbuf @3712, trh @3904.
// ---------------------------------------------------------------------------
__global__ __launch_bounds__(256) void fused_main(
    const float* __restrict__ state, const short* __restrict__ pk,
    const float* __restrict__ wr_w1, const float* __restrict__ wr_b1,
    const float* __restrict__ wr_b2, const float* __restrict__ wh_b2,
    short* __restrict__ r2buf)
{
    __shared__ __align__(16) short wbuf[4][4096];

    const int tid = threadIdx.x;
    const int wv = tid >> 6, lane = tid & 63;
    const int q = lane >> 4, c = lane & 15;
    const int b = blockIdx.x * 4 + wv;
    const float* st = state + (size_t)b * 832;
    short* T = wbuf[wv];

    const bf16x8* pk16 = (const bf16x8*)pk;
    const float* bg1f = (const float*)(pk + 52736);
    const float* bg2f = (const float*)(pk + 52864);
    const f32x4 z4 = {0.f, 0.f, 0.f, 0.f};

    bf16x8 A1[4], Bh2v[4], Bev[2];
    #pragma unroll
    for (int i = 0; i < 4; ++i) A1[i] = pk16[i * 64 + lane];
    #pragma unroll
    for (int i = 0; i < 4; ++i) Bh2v[i] = pk16[(4 + i) * 64 + lane];
    #pragma unroll
    for (int i = 0; i < 2; ++i) Bev[i] = pk16[(8 + i) * 64 + lane];

    {   // own human's features -> LDS, B-ready (k=0..6 feats, k=7 -> 1.0)
        float hf[7];
        #pragma unroll
        for (int m = 0; m < 7; ++m) hf[m] = st[lane * 13 + 6 + m];
        uint4 v = make_uint4(pk2(hf[0], hf[1]), pk2(hf[2], hf[3]),
                             pk2(hf[4], hf[5]), pk2(hf[6], 1.0f));
        *(uint4*)(T + lane * 8) = v;
    }

    float trh;   // r-MLP hidden (lane = hidden unit)
    {
        float acc = wr_b1[lane];
        #pragma unroll
        for (int m = 0; m < 6; ++m) acc = fmaf(st[m], wr_w1[m * 64 + lane], acc);
        trh = fmaxf(acc, 0.f);
    }

    asm volatile("s_waitcnt lgkmcnt(0)" ::: "memory");

    bf16x8 bx[4];
    #pragma unroll
    for (int ht = 0; ht < 4; ++ht) {
        bf16x8 v = zero8();
        if (q == 0) v = *(const bf16x8*)(T + (ht * 16 + c) * 8);
        bx[ht] = v;
    }

    // S1': t^T = Wh1^T @ x^T; paired mh tiles -> one b128 write per (mhp,ht)
    #pragma unroll
    for (int mhp = 0; mhp < 2; ++mhp) {
        #pragma unroll
        for (int ht = 0; ht < 4; ++ht) {
            f32x4 d0 = MFMA16(A1[2 * mhp + 0], bx[ht], z4);
            f32x4 d1 = MFMA16(A1[2 * mhp + 1], bx[ht], z4);
            d0 = __builtin_elementwise_max(d0, z4);
            d1 = __builtin_elementwise_max(d1, z4);
            uint4 w = make_uint4(pk2(d0[0], d0[1]), pk2(d0[2], d0[3]),
                                 pk2(d1[0], d1[1]), pk2(d1[2], d1[3]));
            int row = ht * 16 + c;
            int p = (mhp * 4 + q) ^ (c & 7);
            *(uint4*)(T + row * 64 + p * 8) = w;
        }
    }

    asm volatile("s_waitcnt lgkmcnt(0)" ::: "memory");

    // S2: h = t @ Wh2 (+b2, relu); packed-pair h rows + vector s-accumulators
    const float b2a = wh_b2[c], b2b = wh_b2[16 + c];
    const f32x4 b2a4 = {b2a, b2a, b2a, b2a}, b2b4 = {b2b, b2b, b2b, b2b};
    f32x4 psv0 = z4, psv1 = z4;
    #pragma unroll
    for (int mt = 0; mt < 4; ++mt) {
        int row = mt * 16 + c;
        bf16x8 a0 = *(const bf16x8*)(T + row * 64 + ((q ^ (c & 7))) * 8);
        bf16x8 a1 = *(const bf16x8*)(T + row * 64 + (((q + 4) ^ (c & 7))) * 8);
        f32x4 e0 = MFMA16(a0, Bh2v[0], z4); e0 = MFMA16(a1, Bh2v[2], e0);
        f32x4 e1 = MFMA16(a0, Bh2v[1], z4); e1 = MFMA16(a1, Bh2v[3], e1);
        e0 = __builtin_elementwise_max(e0 + b2a4, z4);
        e1 = __builtin_elementwise_max(e1 + b2b4, z4);
        psv0 += e0; psv1 += e1;
        #pragma unroll
        for (int r = 0; r < 4; ++r) {
            int hrow = mt * 16 + q * 4 + r;
            *(unsigned*)(T + hrow * 32 + (((c >> 2) ^ r)) * 8 + (c & 3) * 2) = pk2(e0[r], e1[r]);
        }
    }
    float ps0 = (psv0[0] + psv0[1]) + (psv0[2] + psv0[3]);
    float ps1 = (psv1[0] + psv1[1]) + (psv1[2] + psv1[3]);
    ps0 += __shfl_xor(ps0, 16); ps0 += __shfl_xor(ps0, 32);
    ps1 += __shfl_xor(ps1, 16); ps1 += __shfl_xor(ps1, 32);

    {   // s -> sbuf: [s_hi;s_lo;r_hi;r_lo;s_hi;r_hi], trh -> [hi;lo;hi]
        short* SB = T + 3712;
        if (q == 0) {
            unsigned short h0 = bfhi(ps0), h1 = bfhi(ps1);
            SB[c] = (short)h0;        SB[16 + c] = (short)h1;
            SB[32 + c] = (short)bfhi(ps0 - b2f(h0));
            SB[48 + c] = (short)bfhi(ps1 - b2f(h1));
            SB[128 + c] = (short)h0;  SB[144 + c] = (short)h1;
        }
        short* TR = T + 3904;
        unsigned short th = bfhi(trh);
        TR[lane] = (short)th;
        TR[64 + lane] = (short)bfhi(trh - b2f(th));
        TR[128 + lane] = (short)th;
    }
    __syncthreads();   // B1

    if (wv == 0) {     // rL2 + glue1 for the block's 4 rows (split-bf16 K=192)
        bf16x8 art[6];
        #pragma unroll
        for (int ks = 0; ks < 6; ++ks) {
            bf16x8 v = zero8();
            if (c < 4) v = *(const bf16x8*)(wbuf[c] + 3904 + ks * 32 + q * 8);
            art[ks] = v;
        }
        f32x4 dr0 = z4, dr1 = z4;
        #pragma unroll
        for (int ks = 0; ks < 6; ++ks) {
            dr0 = MFMA16(art[ks], pk16[(10 + ks * 2 + 0) * 64 + lane], dr0);
            dr1 = MFMA16(art[ks], pk16[(10 + ks * 2 + 1) * 64 + lane], dr1);
        }
        const float wb0 = wr_b2[c], wb1 = wr_b2[16 + c];
        if (q == 0) {
            #pragma unroll
            for (int r = 0; r < 4; ++r) {
                float v0 = fmaxf(dr0[r] + wb0, 0.f), v1 = fmaxf(dr1[r] + wb1, 0.f);
                short* SBr = wbuf[r] + 3712;
                unsigned short h0 = bfhi(v0), h1 = bfhi(v1);
                SBr[64 + c] = (short)h0;  SBr[96 + c]  = (short)bfhi(v0 - b2f(h0));  SBr[160 + c] = (short)h0;
                SBr[80 + c] = (short)h1;  SBr[112 + c] = (short)bfhi(v1 - b2f(h1));  SBr[176 + c] = (short)h1;
            }
        }
        asm volatile("s_waitcnt lgkmcnt(0)" ::: "memory");

        bf16x8 ag[6];
        #pragma unroll
        for (int ks = 0; ks < 6; ++ks) {
            bf16x8 v = zero8();
            if (c < 4) v = *(const bf16x8*)(wbuf[c] + 3712 + ks * 32 + q * 8);
            ag[ks] = v;
        }
        f32x4 dg[4] = {z4, z4, z4, z4};
        #pragma unroll
        for (int ks = 0; ks < 6; ++ks) {
            #pragma unroll
            for (int nt = 0; nt < 4; ++nt)
                dg[nt] = MFMA16(ag[ks], pk16[(22 + ks * 4 + nt) * 64 + lane], dg[nt]);
        }
        if (q == 0) {
            #pragma unroll
            for (int nt = 0; nt < 2; ++nt) {
                float bias = bg1f[nt * 16 + c];
                #pragma unroll
                for (int r = 0; r < 4; ++r) {       // r1 -> g2in
                    float v = fmaxf(dg[nt][r] + bias, 0.f);
                    short* G2r = wbuf[r] + 3520;
                    unsigned short hh = bfhi(v);
                    G2r[64 + nt * 16 + c]  = (short)hh;
                    G2r[96 + nt * 16 + c]  = (short)bfhi(v - b2f(hh));
                    G2r[160 + nt * 16 + c] = (short)hh;
                }
            }
            #pragma unroll
            for (int nt = 2; nt < 4; ++nt) {
                float bias = bg1f[nt * 16 + c];
                #pragma unroll
                for (int r = 0; r < 4; ++r)         // c1 (f32, no relu)
                    ((float*)(wbuf[r] + 3456))[(nt - 2) * 16 + c] = dg[nt][r] + bias;
            }
        }
    }
    __syncthreads();   // B2

    {   // S4: s2 = sum_hu relu(c1 + h @ W1eff)   (h interleaved, Be K-permuted)
        const float* C1 = (const float*)(T + 3456);
        const float c10 = C1[c], c11 = C1[16 + c];
        const f32x4 c10v = {c10, c10, c10, c10}, c11v = {c11, c11, c11, c11};
        f32x4 acc0 = z4, acc1 = z4;
        #pragma unroll
        for (int mt = 0; mt < 4; ++mt) {
            int row = mt * 16 + c;
            bf16x8 ah = *(const bf16x8*)(T + row * 32 + ((q ^ (c & 3))) * 8);
            f32x4 g0 = MFMA16(ah, Bev[0], z4);
            f32x4 g1 = MFMA16(ah, Bev[1], z4);
            acc0 += __builtin_elementwise_max(g0 + c10v, z4);
            acc1 += __builtin_elementwise_max(g1 + c11v, z4);
        }
        float t0 = (acc0[0] + acc0[1]) + (acc0[2] + acc0[3]);
        float t1 = (acc1[0] + acc1[1]) + (acc1[2] + acc1[3]);
        t0 += __shfl_xor(t0, 16); t0 += __shfl_xor(t0, 32);
        t1 += __shfl_xor(t1, 16); t1 += __shfl_xor(t1, 32);
        short* G2 = T + 3520;   // [s2_hi(32); s2_lo(32); r1...; s2_hi(32); r1...]
        if (q == 0) {
            unsigned short h0 = bfhi(t0), h1 = bfhi(t1);
            G2[c] = (short)h0;        G2[16 + c] = (short)h1;
            G2[32 + c] = (short)bfhi(t0 - b2f(h0));
            G2[48 + c] = (short)bfhi(t1 - b2f(h1));
            G2[128 + c] = (short)h0;  G2[144 + c] = (short)h1;
        }
    }
    __syncthreads();   // B3

    if (wv == 0) {     // glue2 -> r2
        bf16x8 a2[6];
        #pragma unroll
        for (int ks = 0; ks < 6; ++ks) {
            bf16x8 v = zero8();
            if (c < 4) v = *(const bf16x8*)(wbuf[c] + 3520 + ks * 32 + q * 8);
            a2[ks] = v;
        }
        f32x4 d0 = z4, d1 = z4;
        #pragma unroll
        for (int ks = 0; ks < 6; ++ks) {
            d0 = MFMA16(a2[ks], pk16[(46 + ks * 2 + 0) * 64 + lane], d0);
            d1 = MFMA16(a2[ks], pk16[(46 + ks * 2 + 1) * 64 + lane], d1);
        }
        if (q == 0) {
            const int b0 = blockIdx.x * 4;
            const float g0 = bg2f[c], g1 = bg2f[16 + c];
            #pragma unroll
            for (int r = 0; r < 4; ++r) {
                r2buf[(b0 + r) * 32 + c]      = f2s(fmaxf(d0[r] + g0, 0.f));
                r2buf[(b0 + r) * 32 + 16 + c] = f2s(fmaxf(d1[r] + g1, 0.f));
            }
        }
    }
}

// ---------------------------------------------------------------------------
__global__ __launch_bounds__(256) void head_kernel(
    const short* __restrict__ pk,
    const float* __restrict__ vn_b1, const float* __restrict__ vn_b2,
    const float* __restrict__ vn_w3, const float* __restrict__ vn_b3,
    float* __restrict__ out)
{
    __shared__ __align__(16) short sh_v1[4][16 * 168];
    const int wv = threadIdx.x >> 6, lane = threadIdx.x & 63;
    const int q = lane >> 4, c = lane & 15;
    const int tile = blockIdx.x * 4 + wv;
    const bf16x8* wf = (const bf16x8*)pk;
    const short* r2b = pk + 53248;
    const f32x4 z4 = {0.f, 0.f, 0.f, 0.f};

    bf16x8 a1 = *(const bf16x8*)&r2b[(tile * 16 + c) * 32 + q * 8];
    short* vb = sh_v1[wv];
    #pragma unroll
    for (int nt = 0; nt < 10; ++nt) {
        f32x4 d = MFMA16(a1, wf[(58 + nt) * 64 + lane], z4);
        int n = nt * 16 + c;
        float bias = (n < 150) ? vn_b1[n] : 0.f;
        #pragma unroll
        for (int r = 0; r < 4; ++r) {
            float v = (n < 150) ? fmaxf(d[r] + bias, 0.f) : 0.f;
            vb[(q * 4 + r) * 168 + n] = f2s(v);
        }
    }
    __syncthreads();

    bf16x8 a2[5];
    #pragma unroll
    for (int kt = 0; kt < 5; ++kt)
        a2[kt] = *(const bf16x8*)&vb[c * 168 + kt * 32 + q * 8];

    float racc[4] = {0.f, 0.f, 0.f, 0.f};
    #pragma unroll
    for (int nt = 0; nt < 7; ++nt) {
        f32x4 d = z4;
        #pragma unroll
        for (int kt = 0; kt < 5; ++kt)
            d = MFMA16(a2[kt], wf[(68 + kt * 7 + nt) * 64 + lane], d);
        int n = nt * 16 + c;
        float bias = (n < 100) ? vn_b2[n] : 0.f;
        float w3   = (n < 100) ? vn_w3[n] : 0.f;
        #pragma unroll
        for (int r = 0; r < 4; ++r) racc[r] += fmaxf(d[r] + bias, 0.f) * w3;
    }
    #pragma unroll
    for (int m = 1; m < 16; m <<= 1) {
        #pragma unroll
        for (int r = 0; r < 4; ++r) racc[r] += __shfl_xor(racc[r], m);
    }
    if (c == 0) {
        float b3 = vn_b3[0];
        #pragma unroll
        for (int r = 0; r < 4; ++r) out[tile * 16 + q * 4 + r] = racc[r] + b3;
    }
}

// ---------------------------------------------------------------------------
extern "C" void kernel_launch(void* const* d_in, const int* in_sizes, int n_in,
                              void* d_out, int out_size, void* d_ws, size_t ws_size,
                              hipStream_t stream) {
    const float* state    = (const float*)d_in[0];
    const float* wr_w1    = (const float*)d_in[2];
    const float* wr_b1    = (const float*)d_in[3];
    const float* wr_w2    = (const float*)d_in[4];
    const float* wr_b2    = (const float*)d_in[5];
    const float* wh_w1    = (const float*)d_in[6];
    const float* wh_b1    = (const float*)d_in[7];
    const float* wh_w2    = (const float*)d_in[8];
    const float* wh_b2    = (const float*)d_in[9];
    const float* rel_rh1  = (const float*)d_in[10];
    const float* brel_rh1 = (const float*)d_in[11];
    const float* root_rh1 = (const float*)d_in[12];
    const float* rel_hr1  = (const float*)d_in[13];
    const float* brel_hr1 = (const float*)d_in[14];
    const float* root_hr1 = (const float*)d_in[15];
    const float* rel_hh1  = (const float*)d_in[16];
    const float* brel_hh1 = (const float*)d_in[17];
    const float* root_hh1 = (const float*)d_in[18];
    // 19..21, 25..27 dead (layer-2 new_h unused)
    const float* rel_hr2  = (const float*)d_in[22];
    const float* brel_hr2 = (const float*)d_in[23];
    const float* root_hr2 = (const float*)d_in[24];
    const float* vn_w1    = (const float*)d_in[28];
    const float* vn_b1    = (const float*)d_in[29];
    const float* vn_w2    = (const float*)d_in[30];
    const float* vn_b2    = (const float*)d_in[31];
    const float* vn_w3    = (const float*)d_in[32];
    const float* vn_b3    = (const float*)d_in[33];
    float* out = (float*)d_out;
    short* pk  = (short*)d_ws;               // needs ~1.16 MB of workspace
    short* r2buf = pk + 53248;

    pack_frags<<<207, 256, 0, stream>>>(wh_w1, wh_b1, wh_w2,
                                        root_rh1, root_hh1, rel_hh1, wr_w2,
                                        rel_hr1, root_hr1, rel_rh1,
                                        rel_hr2, root_hr2, vn_w1, vn_w2,
                                        brel_hr1, brel_rh1, brel_hh1, brel_hr2, pk);
    fused_main<<<BTOT / 4, 256, 0, stream>>>(state, pk, wr_w1, wr_b1, wr_b2, wh_b2, r2buf);
    head_kernel<<<BTOT / 64, 256, 0, stream>>>(pk, vn_b1, vn_b2, vn_w3, vn_b3, out);
}